// Round 8
// baseline (257.454 us; speedup 1.0000x reference)
//
#include <hip/hip_runtime.h>

// MHA block on gfx950: qkv = x@Wa+ba; causal attention (static softmax); out = o@Wp+bp.
// B=4, L=2048, D=1024, H=16, Hd=64. bf16 MFMA 16x16x32, fp32 accumulation.
// R13: attn KVBLK 128 -> 256: halves sync points (18 -> 9 vmcnt(0)+barrier per
// block) at identical HBM traffic; all chunk math generalizes (kc 0..7,
// dmc = 8qb+wid-8j, clamp 8). LDS 64 -> 128 KB (still 1 block/CU persistent).
// exp2 path: Q pre-scale folds log2e (0.125 -> 0.125*log2e), attn uses exp2f
// (native v_exp_f32), saving 32 v_mul/lane/chunk.
// GEMMs frozen at R12 (128^2, persistent, V^T uint2-packed epilogue, 67us).

typedef __attribute__((ext_vector_type(8))) short short8;   // 8 bf16
typedef __attribute__((ext_vector_type(4))) short s16x4;    // 4 bf16
typedef __attribute__((ext_vector_type(4))) float f32x4;    // MFMA C/D frag

#define DEVI __device__ __forceinline__

constexpr int NE = 1024, NH = 16, NB = 4, L = 2048;
constexpr int M = NB * L;       // 8192 tokens
constexpr int KD = 1024;        // GEMM K (both GEMMs)

DEVI unsigned f2bf(float f) {
    union { float f; unsigned u; } v; v.f = f;
    unsigned u = v.u;
    u += 0x7fffu + ((u >> 16) & 1u);   // RNE
    return u >> 16;
}
DEVI unsigned pack_bf2(float lo, float hi) {   // round-half-up, 2 floats -> 1 dword
    union { float f; unsigned u; } a, b; a.f = lo; b.f = hi;
    return ((a.u + 0x8000u) >> 16) | ((b.u + 0x8000u) & 0xffff0000u);
}

typedef const __attribute__((address_space(1))) void* gas_t;
typedef __attribute__((address_space(3))) void* las_t;
DEVI void gl_lds16(const void* g, void* l) {
    __builtin_amdgcn_global_load_lds((gas_t)g, (las_t)l, 16, 0, 0);
}

// ---------- merged prep: x fp32->bf16 convert + Wa^T + Wp^T ----------
// grid partition: [0,4096) convert; [4096,7168) Wa transpose (96x32);
// [7168,8192) Wp transpose (32x32). 256 threads each.
DEVI void transpose_tile(const float* __restrict__ in, unsigned short* __restrict__ out,
                         int R, int C, int bx, int by, int tid, float* t /*[32*33]*/) {
    const int tx = tid & 31, ty = tid >> 5;
    const int x = bx * 32 + tx;
    const int y0 = by * 32;
#pragma unroll
    for (int i = 0; i < 4; i++)
        t[(ty + 8 * i) * 33 + tx] = in[(size_t)(y0 + ty + 8 * i) * C + x];
    __syncthreads();
    const int xo = y0 + tx;
    const int yo = bx * 32 + ty;
#pragma unroll
    for (int i = 0; i < 4; i++)
        out[(size_t)(yo + 8 * i) * R + xo] = f2bf(t[tx * 33 + ty + 8 * i]);
}

__global__ __launch_bounds__(256)
void k_prep(const float* __restrict__ x, unsigned short* __restrict__ xb,
            const float* __restrict__ Wa, unsigned short* __restrict__ WaT,
            const float* __restrict__ Wp, unsigned short* __restrict__ WpT) {
    __shared__ float t[32 * 33];
    const int blk = (int)blockIdx.x;
    const int tid = threadIdx.x;
    if (blk < 4096) {
        const int i = blk * 256 + tid;              // i < 1,048,576 = M*NE/8
        const float4* p = (const float4*)x + (size_t)i * 2;
        float4 a = p[0], b = p[1];
        short8 r;
        r[0] = f2bf(a.x); r[1] = f2bf(a.y); r[2] = f2bf(a.z); r[3] = f2bf(a.w);
        r[4] = f2bf(b.x); r[5] = f2bf(b.y); r[6] = f2bf(b.z); r[7] = f2bf(b.w);
        ((short8*)xb)[i] = r;
    } else if (blk < 4096 + 3072) {
        const int id = blk - 4096;                  // Wa: [NE][3NE] -> [3NE][NE]
        transpose_tile(Wa, WaT, NE, 3 * NE, id % 96, id / 96, tid, t);
    } else {
        const int id = blk - 7168;                  // Wp: [NE][NE] -> [NE][NE]
        transpose_tile(Wp, WpT, NE, NE, id % 32, id / 32, tid, t);
    }
}

// ---------- 128x128 bf16 GEMM, BK=64, swizzled LDS (R5 structure) ----------
// LDS slot s of row r holds global k-seg s^(r&7)  (seg = 16B = 8 bf16).
// Persistent: MODE0 grid 768 x 2 tiles (pair shares n-column); MODE1 grid 512 x 1.
template <int MODE>
__global__ __launch_bounds__(256, 4)
void k_gemm(const unsigned short* __restrict__ A,
            const unsigned short* __restrict__ Bt,
            const float* __restrict__ bias,
            unsigned short* __restrict__ Qb,
            unsigned short* __restrict__ Kb,
            unsigned short* __restrict__ Vt,
            float* __restrict__ out) {
    constexpr int NBN  = (MODE == 0) ? 24 : 8;     // n-blocks
    constexpr int GRID = (MODE == 0) ? 768 : 512;
    constexpr int REPS = (MODE == 0) ? 2 : 1;

    __shared__ alignas(16) short As[128 * 64];
    __shared__ alignas(16) short Bs[128 * 64];
    const int tid = threadIdx.x;
    const int lane = tid & 63, wid = tid >> 6;
    const int quad = lane >> 4, l16 = lane & 15;
    const int wm = (wid >> 1) * 64, wn = (wid & 1) * 64;

    const int srow = lane >> 3;              // 8 rows per wave-call
    const int gseg = (lane & 7) ^ srow;      // swizzled global seg

    // XCD-bijective swizzle (GRID % 8 == 0)
    const int p = (int)blockIdx.x;
    const int ps = (p & 7) * (GRID / 8) + (p >> 3);

    for (int rep = 0; rep < REPS; rep++) {
        const int t = ps + rep * GRID;
        const int n0 = (t % NBN) * 128;
        const int m0 = (t / NBN) * 128;

        f32x4 acc[4][4] = {};

        for (int kk = 0; kk < KD; kk += 64) {
            __syncthreads();
#pragma unroll
            for (int c = 0; c < 4; c++) {
                const int rbase = c * 32 + wid * 8;
                gl_lds16(&A[(size_t)(m0 + rbase + srow) * KD + kk + gseg * 8], &As[rbase * 64]);
                gl_lds16(&Bt[(size_t)(n0 + rbase + srow) * KD + kk + gseg * 8], &Bs[rbase * 64]);
            }
            __syncthreads();
#pragma unroll
            for (int kc = 0; kc < 2; kc++) {
                short8 af[4], bf[4];
#pragma unroll
                for (int tt = 0; tt < 4; tt++) {
                    const int Ra = wm + tt * 16 + l16;
                    af[tt] = *(const short8*)&As[Ra * 64 + (((kc * 4 + quad) ^ (Ra & 7)) * 8)];
                    const int Rb = wn + tt * 16 + l16;
                    bf[tt] = *(const short8*)&Bs[Rb * 64 + (((kc * 4 + quad) ^ (Rb & 7)) * 8)];
                }
#pragma unroll
                for (int mt = 0; mt < 4; mt++)
#pragma unroll
                    for (int nt = 0; nt < 4; nt++)
                        acc[mt][nt] = __builtin_amdgcn_mfma_f32_16x16x32_bf16(
                            af[mt], bf[nt], acc[mt][nt], 0, 0, 0);
            }
        }

#pragma unroll
        for (int nt = 0; nt < 4; nt++) {
            const int n = n0 + wn + nt * 16 + l16;
            const float bv = bias[n];
            if (MODE == 0) {
                const int sel = n >> 10;                  // 0=Q 1=K 2=V (block-uniform)
                const int h = (n & 1023) >> 6;
                const int d = n & 63;
                if (sel == 2) {
                    // V^T: each thread's 4 r-values are contiguous in Vt -> one uint2
#pragma unroll
                    for (int mt = 0; mt < 4; mt++) {
                        const int m = m0 + wm + mt * 16 + quad * 4;   // r base
                        const int b = m >> 11, l = m & 2047;
                        const int bh = b * NH + h;
                        const float v0 = acc[mt][nt][0] + bv;
                        const float v1 = acc[mt][nt][1] + bv;
                        const float v2 = acc[mt][nt][2] + bv;
                        const float v3 = acc[mt][nt][3] + bv;
                        const unsigned w0 = f2bf(v0) | (f2bf(v1) << 16);
                        const unsigned w1 = f2bf(v2) | (f2bf(v3) << 16);
                        *(uint2*)&Vt[(size_t)(bh * 64 + d) * L + l] = make_uint2(w0, w1);
                    }
                } else {
                    // Q pre-scale folds log2(e): attn uses exp2 (native v_exp_f32)
                    const float qs = 0.125f * 1.44269504f;
#pragma unroll
                    for (int mt = 0; mt < 4; mt++)
#pragma unroll
                        for (int r = 0; r < 4; r++) {
                            const int m = m0 + wm + mt * 16 + quad * 4 + r;
                            const int b = m >> 11, l = m & 2047;
                            const int bh = b * NH + h;
                            const float v = acc[mt][nt][r] + bv;
                            if (sel == 0) Qb[(size_t)(bh * L + l) * 64 + d] = f2bf(v * qs);
                            else          Kb[(size_t)(bh * L + l) * 64 + d] = f2bf(v);
                        }
                }
            } else {
#pragma unroll
                for (int mt = 0; mt < 4; mt++)
#pragma unroll
                    for (int r = 0; r < 4; r++) {
                        const int m = m0 + wm + mt * 16 + quad * 4 + r;
                        out[(size_t)m * NE + n] = acc[mt][nt][r] + bv;
                    }
            }
        }
    }
}

// ---------- causal attention, static softmax, S^T formulation ----------
// R13: persistent-paired blocks (R10) with KVBLK=256. Grid 256 (1/CU), block
// p=(bh,i): q-tile qb=7-i then qb=i (9 KV-tiles each). Per q-tile: 256 q rows,
// 8 waves, wave = 32 q rows. K/V tiles of 256, double-buffered (128 KB LDS).
// Tile j+1 staged at top of iter j after raw s_barrier; waited vmcnt(0)+
// s_barrier a full iteration later -> 9 drains/block (was 18). S^T = K Q^T:
// P in C-layout with lane = q-col == B-operand shape (k-permutation matched
// by V's A-operand). O^T in regs; LDS transpose restores coalesced stores.
// K LDS [256][64]: seg^(row&7); V LDS [64][256]: seg^(row&15). Bank-clean.
__global__ __launch_bounds__(512, 2)
void k_attn(const unsigned short* __restrict__ Q,   // [BH][L][64], pre-scaled log2e/8
            const unsigned short* __restrict__ Kb,  // [BH][L][64]
            const unsigned short* __restrict__ Vt,  // [BH][64][L]
            unsigned short* __restrict__ O) {       // [B][L][NE] bf16
    __shared__ alignas(16) short smem[65536];       // K[2][16384] | V[2][16384]; Os[256*72] overlays
    short* Os = smem;

    const int tid = threadIdx.x;
    const int lane = tid & 63, wid = tid >> 6;       // wid 0..7
    const int quad = lane >> 4, l16 = lane & 15;
    const int p = (int)blockIdx.x;
    const int bh = p >> 2, pi = p & 3;
    const size_t base = (size_t)bh * L * 64;
    const int b = bh >> 4, h = bh & 15;

    const int srowK = lane >> 3;                     // K: 8 rows per gl_lds
    const int gsegK = (lane & 7) ^ srowK;            // K staging swizzle (row&7)
    const int vrow_off = lane >> 5;                  // V: 2 rows per gl_lds (32 segs/row)
    const int vseg = lane & 31;

    auto stK = [&](int j, int buf) {                 // 256 rows x 64 cols
#pragma unroll
        for (int c = 0; c < 4; c++) {
            const int rbase = c * 64 + wid * 8;
            gl_lds16(&Kb[base + (size_t)(j * 256 + rbase + srowK) * 64 + gsegK * 8],
                     &smem[buf * 16384 + rbase * 64]);
        }
    };
    auto stV = [&](int j, int buf) {                 // 64 rows x 256 cols
#pragma unroll
        for (int c = 0; c < 4; c++) {
            const int rbase = c * 16 + wid * 2;
            const int row = rbase + vrow_off;
            const int gs = vseg ^ (row & 15);
            gl_lds16(&Vt[base + (size_t)row * L + j * 256 + gs * 8],
                     &smem[32768 + buf * 16384 + rbase * 256]);
        }
    };

    for (int half = 0; half < 2; half++) {
        const int qb = half ? pi : 7 - pi;           // heavy tile first
        const int q0 = qb * 256 + wid * 32;
        const int nkv = qb + 1;                      // k/v tiles of 256

        // previous half's O-store LDS reads are retired before restaging
        __syncthreads();
        stK(0, 0); stV(0, 0);

        short8 qf[2][2];
#pragma unroll
        for (int mt = 0; mt < 2; mt++)
#pragma unroll
            for (int dc = 0; dc < 2; dc++)
                qf[mt][dc] = *(const short8*)&Q[base + (size_t)(q0 + mt * 16 + l16) * 64 + dc * 32 + quad * 8];

        f32x4 o[2][4] = {};
        float lrow[2] = {0.f, 0.f};

        for (int j = 0; j < nkv; j++) {
            // K(j),V(j) were issued a full iteration ago (or just above).
            asm volatile("s_waitcnt vmcnt(0)" ::: "memory");
            __builtin_amdgcn_s_barrier();
            // Buffers (j+1)&1 are dead (their readers finished before this barrier).
            if (j < nkv - 1) { stK(j + 1, (j + 1) & 1); stV(j + 1, (j + 1) & 1); }

            const short* Ks = &smem[(j & 1) * 16384];
            const short* Vs = &smem[32768 + (j & 1) * 16384];

            const int dmc = 8 * qb + wid - 8 * j;    // diag chunk (k_start == q_start)
            int chunks = dmc + 1;
            chunks = chunks < 0 ? 0 : (chunks > 8 ? 8 : chunks);

            for (int kc = 0; kc < chunks; kc++) {
                // K fragments (A-operand rows = k)
                short8 kf[2][2];
#pragma unroll
                for (int j0 = 0; j0 < 2; j0++)
#pragma unroll
                    for (int dc = 0; dc < 2; dc++) {
                        const int R = kc * 32 + j0 * 16 + l16;
                        kf[j0][dc] = *(const short8*)&Ks[R * 64 + (((dc * 4 + quad) ^ (R & 7)) * 8)];
                    }
                // S^T[k][q]
                f32x4 st[2][2];
                __builtin_amdgcn_s_setprio(1);
#pragma unroll
                for (int mt = 0; mt < 2; mt++)
#pragma unroll
                    for (int j0 = 0; j0 < 2; j0++) {
                        f32x4 z = {};
                        z = __builtin_amdgcn_mfma_f32_16x16x32_bf16(kf[j0][0], qf[mt][0], z, 0, 0, 0);
                        z = __builtin_amdgcn_mfma_f32_16x16x32_bf16(kf[j0][1], qf[mt][1], z, 0, 0, 0);
                        st[mt][j0] = z;
                    }
                __builtin_amdgcn_s_setprio(0);
                const bool dm = (kc == dmc);
                // p = exp2(s) (log2e folded into Q); B-operand frags in regs (k-permuted)
                short8 pb[2];
#pragma unroll
                for (int mt = 0; mt < 2; mt++) {
                    float pe[8];
                    float sum = 0.f;
#pragma unroll
                    for (int j0 = 0; j0 < 2; j0++)
#pragma unroll
                        for (int r = 0; r < 4; r++) {
                            float pv = exp2f(st[mt][j0][r]);
                            if (dm) {
                                const int krel = j0 * 16 + quad * 4 + r;
                                const int qrel = mt * 16 + l16;
                                if (krel > qrel) pv = 0.f;
                            }
                            sum += pv;
                            pe[j0 * 4 + r] = pv;
                        }
                    lrow[mt] += sum;
#pragma unroll
                    for (int w = 0; w < 4; w++) {
                        unsigned pk = pack_bf2(pe[2 * w], pe[2 * w + 1]);
                        pb[mt][2 * w] = (short)(pk & 0xffff);
                        pb[mt][2 * w + 1] = (short)(pk >> 16);
                    }
                }
                // O^T += V^T P^T : A = V-frag (k-permuted to match pb)
#pragma unroll
                for (int dt = 0; dt < 4; dt++) {
                    const int R2 = dt * 16 + l16;
                    const int s16a = kc * 4 + (quad >> 1);
                    const int off = (quad & 1) * 4;
                    s16x4 lo = *(const s16x4*)&Vs[R2 * 256 + ((s16a ^ l16) * 8) + off];
                    s16x4 hi = *(const s16x4*)&Vs[R2 * 256 + (((s16a + 2) ^ l16) * 8) + off];
                    short8 vf = __builtin_shufflevector(lo, hi, 0, 1, 2, 3, 4, 5, 6, 7);
                    __builtin_amdgcn_s_setprio(1);
#pragma unroll
                    for (int mt = 0; mt < 2; mt++)
                        o[mt][dt] = __builtin_amdgcn_mfma_f32_16x16x32_bf16(
                            vf, pb[mt], o[mt][dt], 0, 0, 0);
                    __builtin_amdgcn_s_setprio(0);
                }
            }
        }

        // denominators: sum over the 4 quads holding this q-column
        float inv[2];
#pragma unroll
        for (int mt = 0; mt < 2; mt++) {
            float rs = lrow[mt];
            rs += __shfl_xor(rs, 16);
            rs += __shfl_xor(rs, 32);
            inv[mt] = 1.0f / rs;
        }

        // O^T -> LDS transpose -> coalesced global store
        __syncthreads();
#pragma unroll
        for (int mt = 0; mt < 2; mt++) {
            const int ql = wid * 32 + mt * 16 + l16;
#pragma unroll
            for (int dt = 0; dt < 4; dt++) {
                unsigned w0 = f2bf(o[mt][dt][0] * inv[mt]) | (f2bf(o[mt][dt][1] * inv[mt]) << 16);
                unsigned w1 = f2bf(o[mt][dt][2] * inv[mt]) | (f2bf(o[mt][dt][3] * inv[mt]) << 16);
                *(uint2*)&Os[ql * 72 + dt * 16 + quad * 4] = make_uint2(w0, w1);
            }
        }
        __syncthreads();
#pragma unroll
        for (int i2 = 0; i2 < 4; i2++) {
            const int id = i2 * 512 + tid;
            const int row = id >> 3, seg = id & 7;
            short8 v = *(const short8*)&Os[row * 72 + seg * 8];
            const int q = qb * 256 + row;
            *(short8*)&O[(size_t)(b * L + q) * NE + h * 64 + seg * 8] = v;
        }
    }
}

extern "C" void kernel_launch(void* const* d_in, const int* in_sizes, int n_in,
                              void* d_out, int out_size, void* d_ws, size_t ws_size,
                              hipStream_t stream) {
    const float* x  = (const float*)d_in[0];
    const float* Wa = (const float*)d_in[1];
    const float* ba = (const float*)d_in[2];
    const float* Wp = (const float*)d_in[3];
    const float* bp = (const float*)d_in[4];
    float* out = (float*)d_out;

    char* ws = (char*)d_ws;
    unsigned short* xb  = (unsigned short*)(ws);                     // 16 MB; reused as O
    unsigned short* WaT = (unsigned short*)(ws + (16u << 20));       //  6 MB
    unsigned short* WpT = (unsigned short*)(ws + (22u << 20));       //  2 MB
    unsigned short* Qb  = (unsigned short*)(ws + (24u << 20));       // 16 MB [BH][L][64]
    unsigned short* Kb  = (unsigned short*)(ws + (40u << 20));       // 16 MB [BH][L][64]
    unsigned short* Vt  = (unsigned short*)(ws + (56u << 20));       // 16 MB [BH][64][L]

    k_prep<<<dim3(8192), 256, 0, stream>>>(x, xb, Wa, WaT, Wp, WpT);

    k_gemm<0><<<dim3(768), 256, 0, stream>>>(xb, WaT, ba, Qb, Kb, Vt, nullptr);

    unsigned short* Ob = xb;
    k_attn<<<dim3(256), 512, 0, stream>>>(Qb, Kb, Vt, Ob);

    k_gemm<1><<<dim3(512), 256, 0, stream>>>(Ob, WpT, bp, nullptr, nullptr, nullptr, out);
}

// Round 9
// 257.326 us; speedup vs baseline: 1.0005x; 1.0005x over previous
//
#include <hip/hip_runtime.h>

// MHA block on gfx950: qkv = x@Wa+ba; causal attention (static softmax); out = o@Wp+bp.
// B=4, L=2048, D=1024, H=16, Hd=64. bf16 MFMA 16x16x32, fp32 accumulation.
// R14: revert attn to R10's verified KVBLK=128 structure (R13's KVBLK=256 cost
// +17us despite fewer drains -- cause confounded; full revert). Keep the exp2
// rider: Q pre-scale folds log2e (gemm0 epilogue), attn uses exp2f (native
// v_exp_f32, fewer VALU ops; absmax improved to 0.0039 in R13).
// Profiled R13 insight kept for the record: attn is VALU/TRANS-bound
// (VALUBusy 50%, MfmaUtil 16.5%) -- exp+pack dominate, not syncs.
// GEMMs frozen at R12 (128^2 persistent, V^T uint2-packed epilogue, 67us,
// MfmaUtil 31-32%). Prep frozen (merged single launch).

typedef __attribute__((ext_vector_type(8))) short short8;   // 8 bf16
typedef __attribute__((ext_vector_type(4))) short s16x4;    // 4 bf16
typedef __attribute__((ext_vector_type(4))) float f32x4;    // MFMA C/D frag

#define DEVI __device__ __forceinline__

constexpr int NE = 1024, NH = 16, NB = 4, L = 2048;
constexpr int M = NB * L;       // 8192 tokens
constexpr int KD = 1024;        // GEMM K (both GEMMs)

DEVI unsigned f2bf(float f) {
    union { float f; unsigned u; } v; v.f = f;
    unsigned u = v.u;
    u += 0x7fffu + ((u >> 16) & 1u);   // RNE
    return u >> 16;
}
DEVI unsigned pack_bf2(float lo, float hi) {   // round-half-up, 2 floats -> 1 dword
    union { float f; unsigned u; } a, b; a.f = lo; b.f = hi;
    return ((a.u + 0x8000u) >> 16) | ((b.u + 0x8000u) & 0xffff0000u);
}

typedef const __attribute__((address_space(1))) void* gas_t;
typedef __attribute__((address_space(3))) void* las_t;
DEVI void gl_lds16(const void* g, void* l) {
    __builtin_amdgcn_global_load_lds((gas_t)g, (las_t)l, 16, 0, 0);
}

// ---------- merged prep: x fp32->bf16 convert + Wa^T + Wp^T ----------
// grid partition: [0,4096) convert; [4096,7168) Wa transpose (96x32);
// [7168,8192) Wp transpose (32x32). 256 threads each.
DEVI void transpose_tile(const float* __restrict__ in, unsigned short* __restrict__ out,
                         int R, int C, int bx, int by, int tid, float* t /*[32*33]*/) {
    const int tx = tid & 31, ty = tid >> 5;
    const int x = bx * 32 + tx;
    const int y0 = by * 32;
#pragma unroll
    for (int i = 0; i < 4; i++)
        t[(ty + 8 * i) * 33 + tx] = in[(size_t)(y0 + ty + 8 * i) * C + x];
    __syncthreads();
    const int xo = y0 + tx;
    const int yo = bx * 32 + ty;
#pragma unroll
    for (int i = 0; i < 4; i++)
        out[(size_t)(yo + 8 * i) * R + xo] = f2bf(t[tx * 33 + ty + 8 * i]);
}

__global__ __launch_bounds__(256)
void k_prep(const float* __restrict__ x, unsigned short* __restrict__ xb,
            const float* __restrict__ Wa, unsigned short* __restrict__ WaT,
            const float* __restrict__ Wp, unsigned short* __restrict__ WpT) {
    __shared__ float t[32 * 33];
    const int blk = (int)blockIdx.x;
    const int tid = threadIdx.x;
    if (blk < 4096) {
        const int i = blk * 256 + tid;              // i < 1,048,576 = M*NE/8
        const float4* p = (const float4*)x + (size_t)i * 2;
        float4 a = p[0], b = p[1];
        short8 r;
        r[0] = f2bf(a.x); r[1] = f2bf(a.y); r[2] = f2bf(a.z); r[3] = f2bf(a.w);
        r[4] = f2bf(b.x); r[5] = f2bf(b.y); r[6] = f2bf(b.z); r[7] = f2bf(b.w);
        ((short8*)xb)[i] = r;
    } else if (blk < 4096 + 3072) {
        const int id = blk - 4096;                  // Wa: [NE][3NE] -> [3NE][NE]
        transpose_tile(Wa, WaT, NE, 3 * NE, id % 96, id / 96, tid, t);
    } else {
        const int id = blk - 7168;                  // Wp: [NE][NE] -> [NE][NE]
        transpose_tile(Wp, WpT, NE, NE, id % 32, id / 32, tid, t);
    }
}

// ---------- 128x128 bf16 GEMM, BK=64, swizzled LDS (R5 structure) ----------
// LDS slot s of row r holds global k-seg s^(r&7)  (seg = 16B = 8 bf16).
// Persistent: MODE0 grid 768 x 2 tiles (pair shares n-column); MODE1 grid 512 x 1.
template <int MODE>
__global__ __launch_bounds__(256, 4)
void k_gemm(const unsigned short* __restrict__ A,
            const unsigned short* __restrict__ Bt,
            const float* __restrict__ bias,
            unsigned short* __restrict__ Qb,
            unsigned short* __restrict__ Kb,
            unsigned short* __restrict__ Vt,
            float* __restrict__ out) {
    constexpr int NBN  = (MODE == 0) ? 24 : 8;     // n-blocks
    constexpr int GRID = (MODE == 0) ? 768 : 512;
    constexpr int REPS = (MODE == 0) ? 2 : 1;

    __shared__ alignas(16) short As[128 * 64];
    __shared__ alignas(16) short Bs[128 * 64];
    const int tid = threadIdx.x;
    const int lane = tid & 63, wid = tid >> 6;
    const int quad = lane >> 4, l16 = lane & 15;
    const int wm = (wid >> 1) * 64, wn = (wid & 1) * 64;

    const int srow = lane >> 3;              // 8 rows per wave-call
    const int gseg = (lane & 7) ^ srow;      // swizzled global seg

    // XCD-bijective swizzle (GRID % 8 == 0)
    const int p = (int)blockIdx.x;
    const int ps = (p & 7) * (GRID / 8) + (p >> 3);

    for (int rep = 0; rep < REPS; rep++) {
        const int t = ps + rep * GRID;
        const int n0 = (t % NBN) * 128;
        const int m0 = (t / NBN) * 128;

        f32x4 acc[4][4] = {};

        for (int kk = 0; kk < KD; kk += 64) {
            __syncthreads();
#pragma unroll
            for (int c = 0; c < 4; c++) {
                const int rbase = c * 32 + wid * 8;
                gl_lds16(&A[(size_t)(m0 + rbase + srow) * KD + kk + gseg * 8], &As[rbase * 64]);
                gl_lds16(&Bt[(size_t)(n0 + rbase + srow) * KD + kk + gseg * 8], &Bs[rbase * 64]);
            }
            __syncthreads();
#pragma unroll
            for (int kc = 0; kc < 2; kc++) {
                short8 af[4], bf[4];
#pragma unroll
                for (int tt = 0; tt < 4; tt++) {
                    const int Ra = wm + tt * 16 + l16;
                    af[tt] = *(const short8*)&As[Ra * 64 + (((kc * 4 + quad) ^ (Ra & 7)) * 8)];
                    const int Rb = wn + tt * 16 + l16;
                    bf[tt] = *(const short8*)&Bs[Rb * 64 + (((kc * 4 + quad) ^ (Rb & 7)) * 8)];
                }
#pragma unroll
                for (int mt = 0; mt < 4; mt++)
#pragma unroll
                    for (int nt = 0; nt < 4; nt++)
                        acc[mt][nt] = __builtin_amdgcn_mfma_f32_16x16x32_bf16(
                            af[mt], bf[nt], acc[mt][nt], 0, 0, 0);
            }
        }

#pragma unroll
        for (int nt = 0; nt < 4; nt++) {
            const int n = n0 + wn + nt * 16 + l16;
            const float bv = bias[n];
            if (MODE == 0) {
                const int sel = n >> 10;                  // 0=Q 1=K 2=V (block-uniform)
                const int h = (n & 1023) >> 6;
                const int d = n & 63;
                if (sel == 2) {
                    // V^T: each thread's 4 r-values are contiguous in Vt -> one uint2
#pragma unroll
                    for (int mt = 0; mt < 4; mt++) {
                        const int m = m0 + wm + mt * 16 + quad * 4;   // r base
                        const int b = m >> 11, l = m & 2047;
                        const int bh = b * NH + h;
                        const float v0 = acc[mt][nt][0] + bv;
                        const float v1 = acc[mt][nt][1] + bv;
                        const float v2 = acc[mt][nt][2] + bv;
                        const float v3 = acc[mt][nt][3] + bv;
                        const unsigned w0 = f2bf(v0) | (f2bf(v1) << 16);
                        const unsigned w1 = f2bf(v2) | (f2bf(v3) << 16);
                        *(uint2*)&Vt[(size_t)(bh * 64 + d) * L + l] = make_uint2(w0, w1);
                    }
                } else {
                    // Q pre-scale folds log2(e): attn uses exp2 (native v_exp_f32)
                    const float qs = 0.125f * 1.44269504f;
#pragma unroll
                    for (int mt = 0; mt < 4; mt++)
#pragma unroll
                        for (int r = 0; r < 4; r++) {
                            const int m = m0 + wm + mt * 16 + quad * 4 + r;
                            const int b = m >> 11, l = m & 2047;
                            const int bh = b * NH + h;
                            const float v = acc[mt][nt][r] + bv;
                            if (sel == 0) Qb[(size_t)(bh * L + l) * 64 + d] = f2bf(v * qs);
                            else          Kb[(size_t)(bh * L + l) * 64 + d] = f2bf(v);
                        }
                }
            } else {
#pragma unroll
                for (int mt = 0; mt < 4; mt++)
#pragma unroll
                    for (int r = 0; r < 4; r++) {
                        const int m = m0 + wm + mt * 16 + quad * 4 + r;
                        out[(size_t)m * NE + n] = acc[mt][nt][r] + bv;
                    }
            }
        }
    }
}

// ---------- causal attention, static softmax, S^T formulation ----------
// R10 structure (verified best): persistent-paired blocks. Grid 256 (1/CU),
// block p=(bh,i): q-tile qb=7-i then qb=i (9 work-units each). Per tile:
// 256 q rows, 8 waves, wave = 32 q rows, K/V tiles of 128, double-buffered
// (64 KB LDS). Tile j+1 staged at top of iter j after raw s_barrier; waited
// vmcnt(0)+s_barrier a full iteration later. S^T = K Q^T: P in C-layout with
// lane = q-col == B-operand shape (k-permutation matched by V's A-operand).
// O^T in regs; LDS transpose restores coalesced stores.
// K LDS: seg^(row&7); V LDS: seg^(row&15). Bank-clean. exp2 path (R14).
__global__ __launch_bounds__(512, 2)
void k_attn(const unsigned short* __restrict__ Q,   // [BH][L][64], pre-scaled log2e/8
            const unsigned short* __restrict__ Kb,  // [BH][L][64]
            const unsigned short* __restrict__ Vt,  // [BH][64][L]
            unsigned short* __restrict__ O) {       // [B][L][NE] bf16
    __shared__ alignas(16) short smem[32768];       // K[2][8192] | V[2][8192]; Os[256*72] overlays
    short* Os = smem;

    const int tid = threadIdx.x;
    const int lane = tid & 63, wid = tid >> 6;       // wid 0..7
    const int quad = lane >> 4, l16 = lane & 15;
    const int p = (int)blockIdx.x;
    const int bh = p >> 2, pi = p & 3;
    const size_t base = (size_t)bh * L * 64;
    const int b = bh >> 4, h = bh & 15;

    const int srowK = lane >> 3;
    const int gsegK = (lane & 7) ^ srowK;            // K staging swizzle (row&7)
    const int vrow_off = (lane >> 4);                // V staging: 4 rows/instr
    const int vseg = lane & 15;

    auto stK = [&](int j, int buf) {
#pragma unroll
        for (int c = 0; c < 2; c++) {
            const int rbase = c * 64 + wid * 8;
            gl_lds16(&Kb[base + (size_t)(j * 128 + rbase + srowK) * 64 + gsegK * 8],
                     &smem[buf * 8192 + rbase * 64]);
        }
    };
    auto stV = [&](int j, int buf) {
#pragma unroll
        for (int c = 0; c < 2; c++) {
            const int rbase = c * 32 + wid * 4;
            const int row = rbase + vrow_off;
            const int gs = vseg ^ (row & 15);
            gl_lds16(&Vt[base + (size_t)row * L + j * 128 + gs * 8],
                     &smem[16384 + buf * 8192 + rbase * 128]);
        }
    };

    for (int half = 0; half < 2; half++) {
        const int qb = half ? pi : 7 - pi;           // heavy tile first
        const int q0 = qb * 256 + wid * 32;
        const int nkv = 2 * qb + 2;                  // k/v tiles of 128

        // previous half's O-store LDS reads are retired before restaging
        __syncthreads();
        stK(0, 0); stV(0, 0);

        short8 qf[2][2];
#pragma unroll
        for (int mt = 0; mt < 2; mt++)
#pragma unroll
            for (int dc = 0; dc < 2; dc++)
                qf[mt][dc] = *(const short8*)&Q[base + (size_t)(q0 + mt * 16 + l16) * 64 + dc * 32 + quad * 8];

        f32x4 o[2][4] = {};
        float lrow[2] = {0.f, 0.f};

        for (int j = 0; j < nkv; j++) {
            // K(j),V(j) were issued a full iteration ago (or just above).
            asm volatile("s_waitcnt vmcnt(0)" ::: "memory");
            __builtin_amdgcn_s_barrier();
            // Buffers (j+1)&1 are dead (their readers finished before this barrier).
            if (j < nkv - 1) { stK(j + 1, (j + 1) & 1); stV(j + 1, (j + 1) & 1); }

            const short* Ks = &smem[(j & 1) * 8192];
            const short* Vs = &smem[16384 + (j & 1) * 8192];

            const int dmc = 8 * qb + wid - 4 * j;    // diag chunk (k_start == q_start)
            int chunks = dmc + 1;
            chunks = chunks < 0 ? 0 : (chunks > 4 ? 4 : chunks);

            for (int kc = 0; kc < chunks; kc++) {
                // K fragments (A-operand rows = k)
                short8 kf[2][2];
#pragma unroll
                for (int j0 = 0; j0 < 2; j0++)
#pragma unroll
                    for (int dc = 0; dc < 2; dc++) {
                        const int R = kc * 32 + j0 * 16 + l16;
                        kf[j0][dc] = *(const short8*)&Ks[R * 64 + (((dc * 4 + quad) ^ (R & 7)) * 8)];
                    }
                // S^T[k][q]
                f32x4 st[2][2];
                __builtin_amdgcn_s_setprio(1);
#pragma unroll
                for (int mt = 0; mt < 2; mt++)
#pragma unroll
                    for (int j0 = 0; j0 < 2; j0++) {
                        f32x4 z = {};
                        z = __builtin_amdgcn_mfma_f32_16x16x32_bf16(kf[j0][0], qf[mt][0], z, 0, 0, 0);
                        z = __builtin_amdgcn_mfma_f32_16x16x32_bf16(kf[j0][1], qf[mt][1], z, 0, 0, 0);
                        st[mt][j0] = z;
                    }
                __builtin_amdgcn_s_setprio(0);
                const bool dm = (kc == dmc);
                // p = exp2(s) (log2e folded into Q); B-operand frags in regs (k-permuted)
                short8 pb[2];
#pragma unroll
                for (int mt = 0; mt < 2; mt++) {
                    float pe[8];
                    float sum = 0.f;
#pragma unroll
                    for (int j0 = 0; j0 < 2; j0++)
#pragma unroll
                        for (int r = 0; r < 4; r++) {
                            float pv = exp2f(st[mt][j0][r]);
                            if (dm) {
                                const int krel = j0 * 16 + quad * 4 + r;
                                const int qrel = mt * 16 + l16;
                                if (krel > qrel) pv = 0.f;
                            }
                            sum += pv;
                            pe[j0 * 4 + r] = pv;
                        }
                    lrow[mt] += sum;
#pragma unroll
                    for (int w = 0; w < 4; w++) {
                        unsigned pk = pack_bf2(pe[2 * w], pe[2 * w + 1]);
                        pb[mt][2 * w] = (short)(pk & 0xffff);
                        pb[mt][2 * w + 1] = (short)(pk >> 16);
                    }
                }
                // O^T += V^T P^T : A = V-frag (k-permuted to match pb)
#pragma unroll
                for (int dt = 0; dt < 4; dt++) {
                    const int R2 = dt * 16 + l16;
                    const int s16a = kc * 4 + (quad >> 1);
                    const int off = (quad & 1) * 4;
                    s16x4 lo = *(const s16x4*)&Vs[R2 * 128 + ((s16a ^ l16) * 8) + off];
                    s16x4 hi = *(const s16x4*)&Vs[R2 * 128 + (((s16a + 2) ^ l16) * 8) + off];
                    short8 vf = __builtin_shufflevector(lo, hi, 0, 1, 2, 3, 4, 5, 6, 7);
                    __builtin_amdgcn_s_setprio(1);
#pragma unroll
                    for (int mt = 0; mt < 2; mt++)
                        o[mt][dt] = __builtin_amdgcn_mfma_f32_16x16x32_bf16(
                            vf, pb[mt], o[mt][dt], 0, 0, 0);
                    __builtin_amdgcn_s_setprio(0);
                }
            }
        }

        // denominators: sum over the 4 quads holding this q-column
        float inv[2];
#pragma unroll
        for (int mt = 0; mt < 2; mt++) {
            float rs = lrow[mt];
            rs += __shfl_xor(rs, 16);
            rs += __shfl_xor(rs, 32);
            inv[mt] = 1.0f / rs;
        }

        // O^T -> LDS transpose -> coalesced global store
        __syncthreads();
#pragma unroll
        for (int mt = 0; mt < 2; mt++) {
            const int ql = wid * 32 + mt * 16 + l16;
#pragma unroll
            for (int dt = 0; dt < 4; dt++) {
                unsigned w0 = f2bf(o[mt][dt][0] * inv[mt]) | (f2bf(o[mt][dt][1] * inv[mt]) << 16);
                unsigned w1 = f2bf(o[mt][dt][2] * inv[mt]) | (f2bf(o[mt][dt][3] * inv[mt]) << 16);
                *(uint2*)&Os[ql * 72 + dt * 16 + quad * 4] = make_uint2(w0, w1);
            }
        }
        __syncthreads();
#pragma unroll
        for (int i2 = 0; i2 < 4; i2++) {
            const int id = i2 * 512 + tid;
            const int row = id >> 3, seg = id & 7;
            short8 v = *(const short8*)&Os[row * 72 + seg * 8];
            const int q = qb * 256 + row;
            *(short8*)&O[(size_t)(b * L + q) * NE + h * 64 + seg * 8] = v;
        }
    }
}

extern "C" void kernel_launch(void* const* d_in, const int* in_sizes, int n_in,
                              void* d_out, int out_size, void* d_ws, size_t ws_size,
                              hipStream_t stream) {
    const float* x  = (const float*)d_in[0];
    const float* Wa = (const float*)d_in[1];
    const float* ba = (const float*)d_in[2];
    const float* Wp = (const float*)d_in[3];
    const float* bp = (const float*)d_in[4];
    float* out = (float*)d_out;

    char* ws = (char*)d_ws;
    unsigned short* xb  = (unsigned short*)(ws);                     // 16 MB; reused as O
    unsigned short* WaT = (unsigned short*)(ws + (16u << 20));       //  6 MB
    unsigned short* WpT = (unsigned short*)(ws + (22u << 20));       //  2 MB
    unsigned short* Qb  = (unsigned short*)(ws + (24u << 20));       // 16 MB [BH][L][64]
    unsigned short* Kb  = (unsigned short*)(ws + (40u << 20));       // 16 MB [BH][L][64]
    unsigned short* Vt  = (unsigned short*)(ws + (56u << 20));       // 16 MB [BH][64][L]

    k_prep<<<dim3(8192), 256, 0, stream>>>(x, xb, Wa, WaT, Wp, WpT);

    k_gemm<0><<<dim3(768), 256, 0, stream>>>(xb, WaT, ba, Qb, Kb, Vt, nullptr);

    unsigned short* Ob = xb;
    k_attn<<<dim3(256), 512, 0, stream>>>(Qb, Kb, Vt, Ob);

    k_gemm<1><<<dim3(512), 256, 0, stream>>>(Ob, WpT, bp, nullptr, nullptr, nullptr, out);
}

// Round 10
// 233.862 us; speedup vs baseline: 1.1009x; 1.1003x over previous
//
#include <hip/hip_runtime.h>

// MHA block on gfx950: qkv = x@Wa+ba; causal attention (static softmax); out = o@Wp+bp.
// B=4, L=2048, D=1024, H=16, Hd=64. bf16 MFMA 16x16x32, fp32 accumulation.
// R15: single fix -- exp2f -> __builtin_amdgcn_exp2f (raw v_exp_f32).
// R14's post-mortem: plain exp2f is the LIBM path (range/denormal handling,
// extra VALU) and cost ~15us in the VALU-bound attn (81.2 vs <=66.6 with
// __expf in R12). The builtin is one v_exp_f32; with log2e folded into the
// Q pre-scale this is strictly cheaper than R12's __expf (v_mul+v_exp).
// Attn otherwise frozen at R10 structure (KVBLK=128, persistent-paired).
// GEMMs frozen at R12 (128^2 persistent, V^T uint2-packed epilogue, 67us).

typedef __attribute__((ext_vector_type(8))) short short8;   // 8 bf16
typedef __attribute__((ext_vector_type(4))) short s16x4;    // 4 bf16
typedef __attribute__((ext_vector_type(4))) float f32x4;    // MFMA C/D frag

#define DEVI __device__ __forceinline__

constexpr int NE = 1024, NH = 16, NB = 4, L = 2048;
constexpr int M = NB * L;       // 8192 tokens
constexpr int KD = 1024;        // GEMM K (both GEMMs)

DEVI unsigned f2bf(float f) {
    union { float f; unsigned u; } v; v.f = f;
    unsigned u = v.u;
    u += 0x7fffu + ((u >> 16) & 1u);   // RNE
    return u >> 16;
}
DEVI unsigned pack_bf2(float lo, float hi) {   // round-half-up, 2 floats -> 1 dword
    union { float f; unsigned u; } a, b; a.f = lo; b.f = hi;
    return ((a.u + 0x8000u) >> 16) | ((b.u + 0x8000u) & 0xffff0000u);
}

typedef const __attribute__((address_space(1))) void* gas_t;
typedef __attribute__((address_space(3))) void* las_t;
DEVI void gl_lds16(const void* g, void* l) {
    __builtin_amdgcn_global_load_lds((gas_t)g, (las_t)l, 16, 0, 0);
}

// ---------- merged prep: x fp32->bf16 convert + Wa^T + Wp^T ----------
// grid partition: [0,4096) convert; [4096,7168) Wa transpose (96x32);
// [7168,8192) Wp transpose (32x32). 256 threads each.
DEVI void transpose_tile(const float* __restrict__ in, unsigned short* __restrict__ out,
                         int R, int C, int bx, int by, int tid, float* t /*[32*33]*/) {
    const int tx = tid & 31, ty = tid >> 5;
    const int x = bx * 32 + tx;
    const int y0 = by * 32;
#pragma unroll
    for (int i = 0; i < 4; i++)
        t[(ty + 8 * i) * 33 + tx] = in[(size_t)(y0 + ty + 8 * i) * C + x];
    __syncthreads();
    const int xo = y0 + tx;
    const int yo = bx * 32 + ty;
#pragma unroll
    for (int i = 0; i < 4; i++)
        out[(size_t)(yo + 8 * i) * R + xo] = f2bf(t[tx * 33 + ty + 8 * i]);
}

__global__ __launch_bounds__(256)
void k_prep(const float* __restrict__ x, unsigned short* __restrict__ xb,
            const float* __restrict__ Wa, unsigned short* __restrict__ WaT,
            const float* __restrict__ Wp, unsigned short* __restrict__ WpT) {
    __shared__ float t[32 * 33];
    const int blk = (int)blockIdx.x;
    const int tid = threadIdx.x;
    if (blk < 4096) {
        const int i = blk * 256 + tid;              // i < 1,048,576 = M*NE/8
        const float4* p = (const float4*)x + (size_t)i * 2;
        float4 a = p[0], b = p[1];
        short8 r;
        r[0] = f2bf(a.x); r[1] = f2bf(a.y); r[2] = f2bf(a.z); r[3] = f2bf(a.w);
        r[4] = f2bf(b.x); r[5] = f2bf(b.y); r[6] = f2bf(b.z); r[7] = f2bf(b.w);
        ((short8*)xb)[i] = r;
    } else if (blk < 4096 + 3072) {
        const int id = blk - 4096;                  // Wa: [NE][3NE] -> [3NE][NE]
        transpose_tile(Wa, WaT, NE, 3 * NE, id % 96, id / 96, tid, t);
    } else {
        const int id = blk - 7168;                  // Wp: [NE][NE] -> [NE][NE]
        transpose_tile(Wp, WpT, NE, NE, id % 32, id / 32, tid, t);
    }
}

// ---------- 128x128 bf16 GEMM, BK=64, swizzled LDS (R5 structure) ----------
// LDS slot s of row r holds global k-seg s^(r&7)  (seg = 16B = 8 bf16).
// Persistent: MODE0 grid 768 x 2 tiles (pair shares n-column); MODE1 grid 512 x 1.
template <int MODE>
__global__ __launch_bounds__(256, 4)
void k_gemm(const unsigned short* __restrict__ A,
            const unsigned short* __restrict__ Bt,
            const float* __restrict__ bias,
            unsigned short* __restrict__ Qb,
            unsigned short* __restrict__ Kb,
            unsigned short* __restrict__ Vt,
            float* __restrict__ out) {
    constexpr int NBN  = (MODE == 0) ? 24 : 8;     // n-blocks
    constexpr int GRID = (MODE == 0) ? 768 : 512;
    constexpr int REPS = (MODE == 0) ? 2 : 1;

    __shared__ alignas(16) short As[128 * 64];
    __shared__ alignas(16) short Bs[128 * 64];
    const int tid = threadIdx.x;
    const int lane = tid & 63, wid = tid >> 6;
    const int quad = lane >> 4, l16 = lane & 15;
    const int wm = (wid >> 1) * 64, wn = (wid & 1) * 64;

    const int srow = lane >> 3;              // 8 rows per wave-call
    const int gseg = (lane & 7) ^ srow;      // swizzled global seg

    // XCD-bijective swizzle (GRID % 8 == 0)
    const int p = (int)blockIdx.x;
    const int ps = (p & 7) * (GRID / 8) + (p >> 3);

    for (int rep = 0; rep < REPS; rep++) {
        const int t = ps + rep * GRID;
        const int n0 = (t % NBN) * 128;
        const int m0 = (t / NBN) * 128;

        f32x4 acc[4][4] = {};

        for (int kk = 0; kk < KD; kk += 64) {
            __syncthreads();
#pragma unroll
            for (int c = 0; c < 4; c++) {
                const int rbase = c * 32 + wid * 8;
                gl_lds16(&A[(size_t)(m0 + rbase + srow) * KD + kk + gseg * 8], &As[rbase * 64]);
                gl_lds16(&Bt[(size_t)(n0 + rbase + srow) * KD + kk + gseg * 8], &Bs[rbase * 64]);
            }
            __syncthreads();
#pragma unroll
            for (int kc = 0; kc < 2; kc++) {
                short8 af[4], bf[4];
#pragma unroll
                for (int tt = 0; tt < 4; tt++) {
                    const int Ra = wm + tt * 16 + l16;
                    af[tt] = *(const short8*)&As[Ra * 64 + (((kc * 4 + quad) ^ (Ra & 7)) * 8)];
                    const int Rb = wn + tt * 16 + l16;
                    bf[tt] = *(const short8*)&Bs[Rb * 64 + (((kc * 4 + quad) ^ (Rb & 7)) * 8)];
                }
#pragma unroll
                for (int mt = 0; mt < 4; mt++)
#pragma unroll
                    for (int nt = 0; nt < 4; nt++)
                        acc[mt][nt] = __builtin_amdgcn_mfma_f32_16x16x32_bf16(
                            af[mt], bf[nt], acc[mt][nt], 0, 0, 0);
            }
        }

#pragma unroll
        for (int nt = 0; nt < 4; nt++) {
            const int n = n0 + wn + nt * 16 + l16;
            const float bv = bias[n];
            if (MODE == 0) {
                const int sel = n >> 10;                  // 0=Q 1=K 2=V (block-uniform)
                const int h = (n & 1023) >> 6;
                const int d = n & 63;
                if (sel == 2) {
                    // V^T: each thread's 4 r-values are contiguous in Vt -> one uint2
#pragma unroll
                    for (int mt = 0; mt < 4; mt++) {
                        const int m = m0 + wm + mt * 16 + quad * 4;   // r base
                        const int b = m >> 11, l = m & 2047;
                        const int bh = b * NH + h;
                        const float v0 = acc[mt][nt][0] + bv;
                        const float v1 = acc[mt][nt][1] + bv;
                        const float v2 = acc[mt][nt][2] + bv;
                        const float v3 = acc[mt][nt][3] + bv;
                        const unsigned w0 = f2bf(v0) | (f2bf(v1) << 16);
                        const unsigned w1 = f2bf(v2) | (f2bf(v3) << 16);
                        *(uint2*)&Vt[(size_t)(bh * 64 + d) * L + l] = make_uint2(w0, w1);
                    }
                } else {
                    // Q pre-scale folds log2(e): attn uses raw v_exp_f32 (2^x)
                    const float qs = 0.125f * 1.44269504f;
#pragma unroll
                    for (int mt = 0; mt < 4; mt++)
#pragma unroll
                        for (int r = 0; r < 4; r++) {
                            const int m = m0 + wm + mt * 16 + quad * 4 + r;
                            const int b = m >> 11, l = m & 2047;
                            const int bh = b * NH + h;
                            const float v = acc[mt][nt][r] + bv;
                            if (sel == 0) Qb[(size_t)(bh * L + l) * 64 + d] = f2bf(v * qs);
                            else          Kb[(size_t)(bh * L + l) * 64 + d] = f2bf(v);
                        }
                }
            } else {
#pragma unroll
                for (int mt = 0; mt < 4; mt++)
#pragma unroll
                    for (int r = 0; r < 4; r++) {
                        const int m = m0 + wm + mt * 16 + quad * 4 + r;
                        out[(size_t)m * NE + n] = acc[mt][nt][r] + bv;
                    }
            }
        }
    }
}

// ---------- causal attention, static softmax, S^T formulation ----------
// R10 structure (verified best): persistent-paired blocks. Grid 256 (1/CU),
// block p=(bh,i): q-tile qb=7-i then qb=i (9 work-units each). Per tile:
// 256 q rows, 8 waves, wave = 32 q rows, K/V tiles of 128, double-buffered
// (64 KB LDS). Tile j+1 staged at top of iter j after raw s_barrier; waited
// vmcnt(0)+s_barrier a full iteration later. S^T = K Q^T: P in C-layout with
// lane = q-col == B-operand shape (k-permutation matched by V's A-operand).
// O^T in regs; LDS transpose restores coalesced stores.
// K LDS: seg^(row&7); V LDS: seg^(row&15). Bank-clean.
// exp path: __builtin_amdgcn_exp2f (raw v_exp_f32; log2e pre-folded in Q).
__global__ __launch_bounds__(512, 2)
void k_attn(const unsigned short* __restrict__ Q,   // [BH][L][64], pre-scaled log2e/8
            const unsigned short* __restrict__ Kb,  // [BH][L][64]
            const unsigned short* __restrict__ Vt,  // [BH][64][L]
            unsigned short* __restrict__ O) {       // [B][L][NE] bf16
    __shared__ alignas(16) short smem[32768];       // K[2][8192] | V[2][8192]; Os[256*72] overlays
    short* Os = smem;

    const int tid = threadIdx.x;
    const int lane = tid & 63, wid = tid >> 6;       // wid 0..7
    const int quad = lane >> 4, l16 = lane & 15;
    const int p = (int)blockIdx.x;
    const int bh = p >> 2, pi = p & 3;
    const size_t base = (size_t)bh * L * 64;
    const int b = bh >> 4, h = bh & 15;

    const int srowK = lane >> 3;
    const int gsegK = (lane & 7) ^ srowK;            // K staging swizzle (row&7)
    const int vrow_off = (lane >> 4);                // V staging: 4 rows/instr
    const int vseg = lane & 15;

    auto stK = [&](int j, int buf) {
#pragma unroll
        for (int c = 0; c < 2; c++) {
            const int rbase = c * 64 + wid * 8;
            gl_lds16(&Kb[base + (size_t)(j * 128 + rbase + srowK) * 64 + gsegK * 8],
                     &smem[buf * 8192 + rbase * 64]);
        }
    };
    auto stV = [&](int j, int buf) {
#pragma unroll
        for (int c = 0; c < 2; c++) {
            const int rbase = c * 32 + wid * 4;
            const int row = rbase + vrow_off;
            const int gs = vseg ^ (row & 15);
            gl_lds16(&Vt[base + (size_t)row * L + j * 128 + gs * 8],
                     &smem[16384 + buf * 8192 + rbase * 128]);
        }
    };

    for (int half = 0; half < 2; half++) {
        const int qb = half ? pi : 7 - pi;           // heavy tile first
        const int q0 = qb * 256 + wid * 32;
        const int nkv = 2 * qb + 2;                  // k/v tiles of 128

        // previous half's O-store LDS reads are retired before restaging
        __syncthreads();
        stK(0, 0); stV(0, 0);

        short8 qf[2][2];
#pragma unroll
        for (int mt = 0; mt < 2; mt++)
#pragma unroll
            for (int dc = 0; dc < 2; dc++)
                qf[mt][dc] = *(const short8*)&Q[base + (size_t)(q0 + mt * 16 + l16) * 64 + dc * 32 + quad * 8];

        f32x4 o[2][4] = {};
        float lrow[2] = {0.f, 0.f};

        for (int j = 0; j < nkv; j++) {
            // K(j),V(j) were issued a full iteration ago (or just above).
            asm volatile("s_waitcnt vmcnt(0)" ::: "memory");
            __builtin_amdgcn_s_barrier();
            // Buffers (j+1)&1 are dead (their readers finished before this barrier).
            if (j < nkv - 1) { stK(j + 1, (j + 1) & 1); stV(j + 1, (j + 1) & 1); }

            const short* Ks = &smem[(j & 1) * 8192];
            const short* Vs = &smem[16384 + (j & 1) * 8192];

            const int dmc = 8 * qb + wid - 4 * j;    // diag chunk (k_start == q_start)
            int chunks = dmc + 1;
            chunks = chunks < 0 ? 0 : (chunks > 4 ? 4 : chunks);

            for (int kc = 0; kc < chunks; kc++) {
                // K fragments (A-operand rows = k)
                short8 kf[2][2];
#pragma unroll
                for (int j0 = 0; j0 < 2; j0++)
#pragma unroll
                    for (int dc = 0; dc < 2; dc++) {
                        const int R = kc * 32 + j0 * 16 + l16;
                        kf[j0][dc] = *(const short8*)&Ks[R * 64 + (((dc * 4 + quad) ^ (R & 7)) * 8)];
                    }
                // S^T[k][q]
                f32x4 st[2][2];
                __builtin_amdgcn_s_setprio(1);
#pragma unroll
                for (int mt = 0; mt < 2; mt++)
#pragma unroll
                    for (int j0 = 0; j0 < 2; j0++) {
                        f32x4 z = {};
                        z = __builtin_amdgcn_mfma_f32_16x16x32_bf16(kf[j0][0], qf[mt][0], z, 0, 0, 0);
                        z = __builtin_amdgcn_mfma_f32_16x16x32_bf16(kf[j0][1], qf[mt][1], z, 0, 0, 0);
                        st[mt][j0] = z;
                    }
                __builtin_amdgcn_s_setprio(0);
                const bool dm = (kc == dmc);
                // p = 2^s (log2e folded into Q); B-operand frags in regs (k-permuted)
                short8 pb[2];
#pragma unroll
                for (int mt = 0; mt < 2; mt++) {
                    float pe[8];
                    float sum = 0.f;
#pragma unroll
                    for (int j0 = 0; j0 < 2; j0++)
#pragma unroll
                        for (int r = 0; r < 4; r++) {
                            float pv = __builtin_amdgcn_exp2f(st[mt][j0][r]);
                            if (dm) {
                                const int krel = j0 * 16 + quad * 4 + r;
                                const int qrel = mt * 16 + l16;
                                if (krel > qrel) pv = 0.f;
                            }
                            sum += pv;
                            pe[j0 * 4 + r] = pv;
                        }
                    lrow[mt] += sum;
#pragma unroll
                    for (int w = 0; w < 4; w++) {
                        unsigned pk = pack_bf2(pe[2 * w], pe[2 * w + 1]);
                        pb[mt][2 * w] = (short)(pk & 0xffff);
                        pb[mt][2 * w + 1] = (short)(pk >> 16);
                    }
                }
                // O^T += V^T P^T : A = V-frag (k-permuted to match pb)
#pragma unroll
                for (int dt = 0; dt < 4; dt++) {
                    const int R2 = dt * 16 + l16;
                    const int s16a = kc * 4 + (quad >> 1);
                    const int off = (quad & 1) * 4;
                    s16x4 lo = *(const s16x4*)&Vs[R2 * 128 + ((s16a ^ l16) * 8) + off];
                    s16x4 hi = *(const s16x4*)&Vs[R2 * 128 + (((s16a + 2) ^ l16) * 8) + off];
                    short8 vf = __builtin_shufflevector(lo, hi, 0, 1, 2, 3, 4, 5, 6, 7);
                    __builtin_amdgcn_s_setprio(1);
#pragma unroll
                    for (int mt = 0; mt < 2; mt++)
                        o[mt][dt] = __builtin_amdgcn_mfma_f32_16x16x32_bf16(
                            vf, pb[mt], o[mt][dt], 0, 0, 0);
                    __builtin_amdgcn_s_setprio(0);
                }
            }
        }

        // denominators: sum over the 4 quads holding this q-column
        float inv[2];
#pragma unroll
        for (int mt = 0; mt < 2; mt++) {
            float rs = lrow[mt];
            rs += __shfl_xor(rs, 16);
            rs += __shfl_xor(rs, 32);
            inv[mt] = 1.0f / rs;
        }

        // O^T -> LDS transpose -> coalesced global store
        __syncthreads();
#pragma unroll
        for (int mt = 0; mt < 2; mt++) {
            const int ql = wid * 32 + mt * 16 + l16;
#pragma unroll
            for (int dt = 0; dt < 4; dt++) {
                unsigned w0 = f2bf(o[mt][dt][0] * inv[mt]) | (f2bf(o[mt][dt][1] * inv[mt]) << 16);
                unsigned w1 = f2bf(o[mt][dt][2] * inv[mt]) | (f2bf(o[mt][dt][3] * inv[mt]) << 16);
                *(uint2*)&Os[ql * 72 + dt * 16 + quad * 4] = make_uint2(w0, w1);
            }
        }
        __syncthreads();
#pragma unroll
        for (int i2 = 0; i2 < 4; i2++) {
            const int id = i2 * 512 + tid;
            const int row = id >> 3, seg = id & 7;
            short8 v = *(const short8*)&Os[row * 72 + seg * 8];
            const int q = qb * 256 + row;
            *(short8*)&O[(size_t)(b * L + q) * NE + h * 64 + seg * 8] = v;
        }
    }
}

extern "C" void kernel_launch(void* const* d_in, const int* in_sizes, int n_in,
                              void* d_out, int out_size, void* d_ws, size_t ws_size,
                              hipStream_t stream) {
    const float* x  = (const float*)d_in[0];
    const float* Wa = (const float*)d_in[1];
    const float* ba = (const float*)d_in[2];
    const float* Wp = (const float*)d_in[3];
    const float* bp = (const float*)d_in[4];
    float* out = (float*)d_out;

    char* ws = (char*)d_ws;
    unsigned short* xb  = (unsigned short*)(ws);                     // 16 MB; reused as O
    unsigned short* WaT = (unsigned short*)(ws + (16u << 20));       //  6 MB
    unsigned short* WpT = (unsigned short*)(ws + (22u << 20));       //  2 MB
    unsigned short* Qb  = (unsigned short*)(ws + (24u << 20));       // 16 MB [BH][L][64]
    unsigned short* Kb  = (unsigned short*)(ws + (40u << 20));       // 16 MB [BH][L][64]
    unsigned short* Vt  = (unsigned short*)(ws + (56u << 20));       // 16 MB [BH][64][L]

    k_prep<<<dim3(8192), 256, 0, stream>>>(x, xb, Wa, WaT, Wp, WpT);

    k_gemm<0><<<dim3(768), 256, 0, stream>>>(xb, WaT, ba, Qb, Kb, Vt, nullptr);

    unsigned short* Ob = xb;
    k_attn<<<dim3(256), 512, 0, stream>>>(Qb, Kb, Vt, Ob);

    k_gemm<1><<<dim3(512), 256, 0, stream>>>(Ob, WpT, bp, nullptr, nullptr, nullptr, out);
}

// Round 11
// 229.929 us; speedup vs baseline: 1.1197x; 1.0171x over previous
//
#include <hip/hip_runtime.h>

// MHA block on gfx950: qkv = x@Wa+ba; causal attention (static softmax); out = o@Wp+bp.
// B=4, L=2048, D=1024, H=16, Hd=64. bf16 MFMA 16x16x32, fp32 accumulation.
// R16: single change -- attn P->bf16 pack via v_cvt_pk_bf16_f32 (inline asm,
// 1 instr/pair, RNE) replacing pack_bf2 (5 VALU ops/pair round-half-up).
// Saves ~32 VALU ops/chunk/lane in the VALU-bound attn (VALUBusy ~52%).
// Matches the documented m214v22 ladder step (+9%) in the identical spot.
// Everything else frozen at R15: GEMMs (128^2 persistent, V^T uint2 epilogue,
// 66.5us, MfmaUtil 32%), attn structure (R10 persistent-paired, KVBLK=128,
// raw v_exp_f32 with log2e folded into Q), merged prep.

typedef __attribute__((ext_vector_type(8))) short short8;   // 8 bf16
typedef __attribute__((ext_vector_type(4))) short s16x4;    // 4 bf16
typedef __attribute__((ext_vector_type(4))) float f32x4;    // MFMA C/D frag

#define DEVI __device__ __forceinline__

constexpr int NE = 1024, NH = 16, NB = 4, L = 2048;
constexpr int M = NB * L;       // 8192 tokens
constexpr int KD = 1024;        // GEMM K (both GEMMs)

DEVI unsigned f2bf(float f) {
    union { float f; unsigned u; } v; v.f = f;
    unsigned u = v.u;
    u += 0x7fffu + ((u >> 16) & 1u);   // RNE
    return u >> 16;
}

typedef const __attribute__((address_space(1))) void* gas_t;
typedef __attribute__((address_space(3))) void* las_t;
DEVI void gl_lds16(const void* g, void* l) {
    __builtin_amdgcn_global_load_lds((gas_t)g, (las_t)l, 16, 0, 0);
}

// ---------- merged prep: x fp32->bf16 convert + Wa^T + Wp^T ----------
// grid partition: [0,4096) convert; [4096,7168) Wa transpose (96x32);
// [7168,8192) Wp transpose (32x32). 256 threads each.
DEVI void transpose_tile(const float* __restrict__ in, unsigned short* __restrict__ out,
                         int R, int C, int bx, int by, int tid, float* t /*[32*33]*/) {
    const int tx = tid & 31, ty = tid >> 5;
    const int x = bx * 32 + tx;
    const int y0 = by * 32;
#pragma unroll
    for (int i = 0; i < 4; i++)
        t[(ty + 8 * i) * 33 + tx] = in[(size_t)(y0 + ty + 8 * i) * C + x];
    __syncthreads();
    const int xo = y0 + tx;
    const int yo = bx * 32 + ty;
#pragma unroll
    for (int i = 0; i < 4; i++)
        out[(size_t)(yo + 8 * i) * R + xo] = f2bf(t[tx * 33 + ty + 8 * i]);
}

__global__ __launch_bounds__(256)
void k_prep(const float* __restrict__ x, unsigned short* __restrict__ xb,
            const float* __restrict__ Wa, unsigned short* __restrict__ WaT,
            const float* __restrict__ Wp, unsigned short* __restrict__ WpT) {
    __shared__ float t[32 * 33];
    const int blk = (int)blockIdx.x;
    const int tid = threadIdx.x;
    if (blk < 4096) {
        const int i = blk * 256 + tid;              // i < 1,048,576 = M*NE/8
        const float4* p = (const float4*)x + (size_t)i * 2;
        float4 a = p[0], b = p[1];
        short8 r;
        r[0] = f2bf(a.x); r[1] = f2bf(a.y); r[2] = f2bf(a.z); r[3] = f2bf(a.w);
        r[4] = f2bf(b.x); r[5] = f2bf(b.y); r[6] = f2bf(b.z); r[7] = f2bf(b.w);
        ((short8*)xb)[i] = r;
    } else if (blk < 4096 + 3072) {
        const int id = blk - 4096;                  // Wa: [NE][3NE] -> [3NE][NE]
        transpose_tile(Wa, WaT, NE, 3 * NE, id % 96, id / 96, tid, t);
    } else {
        const int id = blk - 7168;                  // Wp: [NE][NE] -> [NE][NE]
        transpose_tile(Wp, WpT, NE, NE, id % 32, id / 32, tid, t);
    }
}

// ---------- 128x128 bf16 GEMM, BK=64, swizzled LDS (R5 structure) ----------
// LDS slot s of row r holds global k-seg s^(r&7)  (seg = 16B = 8 bf16).
// Persistent: MODE0 grid 768 x 2 tiles (pair shares n-column); MODE1 grid 512 x 1.
template <int MODE>
__global__ __launch_bounds__(256, 4)
void k_gemm(const unsigned short* __restrict__ A,
            const unsigned short* __restrict__ Bt,
            const float* __restrict__ bias,
            unsigned short* __restrict__ Qb,
            unsigned short* __restrict__ Kb,
            unsigned short* __restrict__ Vt,
            float* __restrict__ out) {
    constexpr int NBN  = (MODE == 0) ? 24 : 8;     // n-blocks
    constexpr int GRID = (MODE == 0) ? 768 : 512;
    constexpr int REPS = (MODE == 0) ? 2 : 1;

    __shared__ alignas(16) short As[128 * 64];
    __shared__ alignas(16) short Bs[128 * 64];
    const int tid = threadIdx.x;
    const int lane = tid & 63, wid = tid >> 6;
    const int quad = lane >> 4, l16 = lane & 15;
    const int wm = (wid >> 1) * 64, wn = (wid & 1) * 64;

    const int srow = lane >> 3;              // 8 rows per wave-call
    const int gseg = (lane & 7) ^ srow;      // swizzled global seg

    // XCD-bijective swizzle (GRID % 8 == 0)
    const int p = (int)blockIdx.x;
    const int ps = (p & 7) * (GRID / 8) + (p >> 3);

    for (int rep = 0; rep < REPS; rep++) {
        const int t = ps + rep * GRID;
        const int n0 = (t % NBN) * 128;
        const int m0 = (t / NBN) * 128;

        f32x4 acc[4][4] = {};

        for (int kk = 0; kk < KD; kk += 64) {
            __syncthreads();
#pragma unroll
            for (int c = 0; c < 4; c++) {
                const int rbase = c * 32 + wid * 8;
                gl_lds16(&A[(size_t)(m0 + rbase + srow) * KD + kk + gseg * 8], &As[rbase * 64]);
                gl_lds16(&Bt[(size_t)(n0 + rbase + srow) * KD + kk + gseg * 8], &Bs[rbase * 64]);
            }
            __syncthreads();
#pragma unroll
            for (int kc = 0; kc < 2; kc++) {
                short8 af[4], bf[4];
#pragma unroll
                for (int tt = 0; tt < 4; tt++) {
                    const int Ra = wm + tt * 16 + l16;
                    af[tt] = *(const short8*)&As[Ra * 64 + (((kc * 4 + quad) ^ (Ra & 7)) * 8)];
                    const int Rb = wn + tt * 16 + l16;
                    bf[tt] = *(const short8*)&Bs[Rb * 64 + (((kc * 4 + quad) ^ (Rb & 7)) * 8)];
                }
#pragma unroll
                for (int mt = 0; mt < 4; mt++)
#pragma unroll
                    for (int nt = 0; nt < 4; nt++)
                        acc[mt][nt] = __builtin_amdgcn_mfma_f32_16x16x32_bf16(
                            af[mt], bf[nt], acc[mt][nt], 0, 0, 0);
            }
        }

#pragma unroll
        for (int nt = 0; nt < 4; nt++) {
            const int n = n0 + wn + nt * 16 + l16;
            const float bv = bias[n];
            if (MODE == 0) {
                const int sel = n >> 10;                  // 0=Q 1=K 2=V (block-uniform)
                const int h = (n & 1023) >> 6;
                const int d = n & 63;
                if (sel == 2) {
                    // V^T: each thread's 4 r-values are contiguous in Vt -> one uint2
#pragma unroll
                    for (int mt = 0; mt < 4; mt++) {
                        const int m = m0 + wm + mt * 16 + quad * 4;   // r base
                        const int b = m >> 11, l = m & 2047;
                        const int bh = b * NH + h;
                        const float v0 = acc[mt][nt][0] + bv;
                        const float v1 = acc[mt][nt][1] + bv;
                        const float v2 = acc[mt][nt][2] + bv;
                        const float v3 = acc[mt][nt][3] + bv;
                        const unsigned w0 = f2bf(v0) | (f2bf(v1) << 16);
                        const unsigned w1 = f2bf(v2) | (f2bf(v3) << 16);
                        *(uint2*)&Vt[(size_t)(bh * 64 + d) * L + l] = make_uint2(w0, w1);
                    }
                } else {
                    // Q pre-scale folds log2(e): attn uses raw v_exp_f32 (2^x)
                    const float qs = 0.125f * 1.44269504f;
#pragma unroll
                    for (int mt = 0; mt < 4; mt++)
#pragma unroll
                        for (int r = 0; r < 4; r++) {
                            const int m = m0 + wm + mt * 16 + quad * 4 + r;
                            const int b = m >> 11, l = m & 2047;
                            const int bh = b * NH + h;
                            const float v = acc[mt][nt][r] + bv;
                            if (sel == 0) Qb[(size_t)(bh * L + l) * 64 + d] = f2bf(v * qs);
                            else          Kb[(size_t)(bh * L + l) * 64 + d] = f2bf(v);
                        }
                }
            } else {
#pragma unroll
                for (int mt = 0; mt < 4; mt++)
#pragma unroll
                    for (int r = 0; r < 4; r++) {
                        const int m = m0 + wm + mt * 16 + quad * 4 + r;
                        out[(size_t)m * NE + n] = acc[mt][nt][r] + bv;
                    }
            }
        }
    }
}

// ---------- causal attention, static softmax, S^T formulation ----------
// R10 structure (verified best): persistent-paired blocks. Grid 256 (1/CU),
// block p=(bh,i): q-tile qb=7-i then qb=i (9 work-units each). Per tile:
// 256 q rows, 8 waves, wave = 32 q rows, K/V tiles of 128, double-buffered
// (64 KB LDS). Tile j+1 staged at top of iter j after raw s_barrier; waited
// vmcnt(0)+s_barrier a full iteration later. S^T = K Q^T: P in C-layout with
// lane = q-col == B-operand shape (k-permutation matched by V's A-operand).
// O^T in regs; LDS transpose restores coalesced stores.
// K LDS: seg^(row&7); V LDS: seg^(row&15). Bank-clean.
// exp: __builtin_amdgcn_exp2f (v_exp_f32; log2e pre-folded in Q).
// P->bf16: v_cvt_pk_bf16_f32 (R16; 1 instr/pair, RNE).
__global__ __launch_bounds__(512, 2)
void k_attn(const unsigned short* __restrict__ Q,   // [BH][L][64], pre-scaled log2e/8
            const unsigned short* __restrict__ Kb,  // [BH][L][64]
            const unsigned short* __restrict__ Vt,  // [BH][64][L]
            unsigned short* __restrict__ O) {       // [B][L][NE] bf16
    __shared__ alignas(16) short smem[32768];       // K[2][8192] | V[2][8192]; Os[256*72] overlays
    short* Os = smem;

    const int tid = threadIdx.x;
    const int lane = tid & 63, wid = tid >> 6;       // wid 0..7
    const int quad = lane >> 4, l16 = lane & 15;
    const int p = (int)blockIdx.x;
    const int bh = p >> 2, pi = p & 3;
    const size_t base = (size_t)bh * L * 64;
    const int b = bh >> 4, h = bh & 15;

    const int srowK = lane >> 3;
    const int gsegK = (lane & 7) ^ srowK;            // K staging swizzle (row&7)
    const int vrow_off = (lane >> 4);                // V staging: 4 rows/instr
    const int vseg = lane & 15;

    auto stK = [&](int j, int buf) {
#pragma unroll
        for (int c = 0; c < 2; c++) {
            const int rbase = c * 64 + wid * 8;
            gl_lds16(&Kb[base + (size_t)(j * 128 + rbase + srowK) * 64 + gsegK * 8],
                     &smem[buf * 8192 + rbase * 64]);
        }
    };
    auto stV = [&](int j, int buf) {
#pragma unroll
        for (int c = 0; c < 2; c++) {
            const int rbase = c * 32 + wid * 4;
            const int row = rbase + vrow_off;
            const int gs = vseg ^ (row & 15);
            gl_lds16(&Vt[base + (size_t)row * L + j * 128 + gs * 8],
                     &smem[16384 + buf * 8192 + rbase * 128]);
        }
    };

    for (int half = 0; half < 2; half++) {
        const int qb = half ? pi : 7 - pi;           // heavy tile first
        const int q0 = qb * 256 + wid * 32;
        const int nkv = 2 * qb + 2;                  // k/v tiles of 128

        // previous half's O-store LDS reads are retired before restaging
        __syncthreads();
        stK(0, 0); stV(0, 0);

        short8 qf[2][2];
#pragma unroll
        for (int mt = 0; mt < 2; mt++)
#pragma unroll
            for (int dc = 0; dc < 2; dc++)
                qf[mt][dc] = *(const short8*)&Q[base + (size_t)(q0 + mt * 16 + l16) * 64 + dc * 32 + quad * 8];

        f32x4 o[2][4] = {};
        float lrow[2] = {0.f, 0.f};

        for (int j = 0; j < nkv; j++) {
            // K(j),V(j) were issued a full iteration ago (or just above).
            asm volatile("s_waitcnt vmcnt(0)" ::: "memory");
            __builtin_amdgcn_s_barrier();
            // Buffers (j+1)&1 are dead (their readers finished before this barrier).
            if (j < nkv - 1) { stK(j + 1, (j + 1) & 1); stV(j + 1, (j + 1) & 1); }

            const short* Ks = &smem[(j & 1) * 8192];
            const short* Vs = &smem[16384 + (j & 1) * 8192];

            const int dmc = 8 * qb + wid - 4 * j;    // diag chunk (k_start == q_start)
            int chunks = dmc + 1;
            chunks = chunks < 0 ? 0 : (chunks > 4 ? 4 : chunks);

            for (int kc = 0; kc < chunks; kc++) {
                // K fragments (A-operand rows = k)
                short8 kf[2][2];
#pragma unroll
                for (int j0 = 0; j0 < 2; j0++)
#pragma unroll
                    for (int dc = 0; dc < 2; dc++) {
                        const int R = kc * 32 + j0 * 16 + l16;
                        kf[j0][dc] = *(const short8*)&Ks[R * 64 + (((dc * 4 + quad) ^ (R & 7)) * 8)];
                    }
                // S^T[k][q]
                f32x4 st[2][2];
                __builtin_amdgcn_s_setprio(1);
#pragma unroll
                for (int mt = 0; mt < 2; mt++)
#pragma unroll
                    for (int j0 = 0; j0 < 2; j0++) {
                        f32x4 z = {};
                        z = __builtin_amdgcn_mfma_f32_16x16x32_bf16(kf[j0][0], qf[mt][0], z, 0, 0, 0);
                        z = __builtin_amdgcn_mfma_f32_16x16x32_bf16(kf[j0][1], qf[mt][1], z, 0, 0, 0);
                        st[mt][j0] = z;
                    }
                __builtin_amdgcn_s_setprio(0);
                const bool dm = (kc == dmc);
                // p = 2^s (log2e folded into Q); pb via v_cvt_pk_bf16_f32 (RNE)
                short8 pb[2];
#pragma unroll
                for (int mt = 0; mt < 2; mt++) {
                    float pe[8];
                    float sum = 0.f;
#pragma unroll
                    for (int j0 = 0; j0 < 2; j0++)
#pragma unroll
                        for (int r = 0; r < 4; r++) {
                            float pv = __builtin_amdgcn_exp2f(st[mt][j0][r]);
                            if (dm) {
                                const int krel = j0 * 16 + quad * 4 + r;
                                const int qrel = mt * 16 + l16;
                                if (krel > qrel) pv = 0.f;
                            }
                            sum += pv;
                            pe[j0 * 4 + r] = pv;
                        }
                    lrow[mt] += sum;
                    union { short8 s; unsigned u[4]; } pbu;
#pragma unroll
                    for (int w = 0; w < 4; w++) {
                        unsigned pk;
                        asm("v_cvt_pk_bf16_f32 %0, %1, %2"
                            : "=v"(pk) : "v"(pe[2 * w]), "v"(pe[2 * w + 1]));
                        pbu.u[w] = pk;
                    }
                    pb[mt] = pbu.s;
                }
                // O^T += V^T P^T : A = V-frag (k-permuted to match pb)
#pragma unroll
                for (int dt = 0; dt < 4; dt++) {
                    const int R2 = dt * 16 + l16;
                    const int s16a = kc * 4 + (quad >> 1);
                    const int off = (quad & 1) * 4;
                    s16x4 lo = *(const s16x4*)&Vs[R2 * 128 + ((s16a ^ l16) * 8) + off];
                    s16x4 hi = *(const s16x4*)&Vs[R2 * 128 + (((s16a + 2) ^ l16) * 8) + off];
                    short8 vf = __builtin_shufflevector(lo, hi, 0, 1, 2, 3, 4, 5, 6, 7);
                    __builtin_amdgcn_s_setprio(1);
#pragma unroll
                    for (int mt = 0; mt < 2; mt++)
                        o[mt][dt] = __builtin_amdgcn_mfma_f32_16x16x32_bf16(
                            vf, pb[mt], o[mt][dt], 0, 0, 0);
                    __builtin_amdgcn_s_setprio(0);
                }
            }
        }

        // denominators: sum over the 4 quads holding this q-column
        float inv[2];
#pragma unroll
        for (int mt = 0; mt < 2; mt++) {
            float rs = lrow[mt];
            rs += __shfl_xor(rs, 16);
            rs += __shfl_xor(rs, 32);
            inv[mt] = 1.0f / rs;
        }

        // O^T -> LDS transpose -> coalesced global store
        __syncthreads();
#pragma unroll
        for (int mt = 0; mt < 2; mt++) {
            const int ql = wid * 32 + mt * 16 + l16;
#pragma unroll
            for (int dt = 0; dt < 4; dt++) {
                unsigned w0 = f2bf(o[mt][dt][0] * inv[mt]) | (f2bf(o[mt][dt][1] * inv[mt]) << 16);
                unsigned w1 = f2bf(o[mt][dt][2] * inv[mt]) | (f2bf(o[mt][dt][3] * inv[mt]) << 16);
                *(uint2*)&Os[ql * 72 + dt * 16 + quad * 4] = make_uint2(w0, w1);
            }
        }
        __syncthreads();
#pragma unroll
        for (int i2 = 0; i2 < 4; i2++) {
            const int id = i2 * 512 + tid;
            const int row = id >> 3, seg = id & 7;
            short8 v = *(const short8*)&Os[row * 72 + seg * 8];
            const int q = qb * 256 + row;
            *(short8*)&O[(size_t)(b * L + q) * NE + h * 64 + seg * 8] = v;
        }
    }
}

extern "C" void kernel_launch(void* const* d_in, const int* in_sizes, int n_in,
                              void* d_out, int out_size, void* d_ws, size_t ws_size,
                              hipStream_t stream) {
    const float* x  = (const float*)d_in[0];
    const float* Wa = (const float*)d_in[1];
    const float* ba = (const float*)d_in[2];
    const float* Wp = (const float*)d_in[3];
    const float* bp = (const float*)d_in[4];
    float* out = (float*)d_out;

    char* ws = (char*)d_ws;
    unsigned short* xb  = (unsigned short*)(ws);                     // 16 MB; reused as O
    unsigned short* WaT = (unsigned short*)(ws + (16u << 20));       //  6 MB
    unsigned short* WpT = (unsigned short*)(ws + (22u << 20));       //  2 MB
    unsigned short* Qb  = (unsigned short*)(ws + (24u << 20));       // 16 MB [BH][L][64]
    unsigned short* Kb  = (unsigned short*)(ws + (40u << 20));       // 16 MB [BH][L][64]
    unsigned short* Vt  = (unsigned short*)(ws + (56u << 20));       // 16 MB [BH][64][L]

    k_prep<<<dim3(8192), 256, 0, stream>>>(x, xb, Wa, WaT, Wp, WpT);

    k_gemm<0><<<dim3(768), 256, 0, stream>>>(xb, WaT, ba, Qb, Kb, Vt, nullptr);

    unsigned short* Ob = xb;
    k_attn<<<dim3(256), 512, 0, stream>>>(Qb, Kb, Vt, Ob);

    k_gemm<1><<<dim3(512), 256, 0, stream>>>(Ob, WpT, bp, nullptr, nullptr, nullptr, out);
}

// Round 12
// 227.325 us; speedup vs baseline: 1.1325x; 1.0115x over previous
//
#include <hip/hip_runtime.h>

// MHA block on gfx950: qkv = x@Wa+ba; causal attention (static softmax); out = o@Wp+bp.
// B=4, L=2048, D=1024, H=16, Hd=64. bf16 MFMA 16x16x32, fp32 accumulation.
// R17: single change -- attn softmax denominator via ones-row MFMA:
// ls[mt] = mfma(ones8, pb[mt], ls[mt]) accumulates sum_k P[k][q] on the MFMA
// pipe (17% utilized) instead of a 16-op v_add chain on the VALU pipe (52%
// busy). With A=ones the D value is k-permutation-invariant and lands at
// col=l16=q, quad-uniform -> the end-of-tile shfl_xor reduce is deleted too.
// Saves ~32 VALU cy/chunk/wave for 2 MFMA on the idle pipe.
// Everything else frozen at R16: GEMMs (128^2 persistent, V^T uint2 epilogue),
// attn structure (R10 persistent-paired, KVBLK=128, v_exp_f32 with log2e
// folded into Q, cvt_pk P->bf16), merged prep.

typedef __attribute__((ext_vector_type(8))) short short8;   // 8 bf16
typedef __attribute__((ext_vector_type(4))) short s16x4;    // 4 bf16
typedef __attribute__((ext_vector_type(4))) float f32x4;    // MFMA C/D frag

#define DEVI __device__ __forceinline__

constexpr int NE = 1024, NH = 16, NB = 4, L = 2048;
constexpr int M = NB * L;       // 8192 tokens
constexpr int KD = 1024;        // GEMM K (both GEMMs)

DEVI unsigned f2bf(float f) {
    union { float f; unsigned u; } v; v.f = f;
    unsigned u = v.u;
    u += 0x7fffu + ((u >> 16) & 1u);   // RNE
    return u >> 16;
}

typedef const __attribute__((address_space(1))) void* gas_t;
typedef __attribute__((address_space(3))) void* las_t;
DEVI void gl_lds16(const void* g, void* l) {
    __builtin_amdgcn_global_load_lds((gas_t)g, (las_t)l, 16, 0, 0);
}

// ---------- merged prep: x fp32->bf16 convert + Wa^T + Wp^T ----------
// grid partition: [0,4096) convert; [4096,7168) Wa transpose (96x32);
// [7168,8192) Wp transpose (32x32). 256 threads each.
DEVI void transpose_tile(const float* __restrict__ in, unsigned short* __restrict__ out,
                         int R, int C, int bx, int by, int tid, float* t /*[32*33]*/) {
    const int tx = tid & 31, ty = tid >> 5;
    const int x = bx * 32 + tx;
    const int y0 = by * 32;
#pragma unroll
    for (int i = 0; i < 4; i++)
        t[(ty + 8 * i) * 33 + tx] = in[(size_t)(y0 + ty + 8 * i) * C + x];
    __syncthreads();
    const int xo = y0 + tx;
    const int yo = bx * 32 + ty;
#pragma unroll
    for (int i = 0; i < 4; i++)
        out[(size_t)(yo + 8 * i) * R + xo] = f2bf(t[tx * 33 + ty + 8 * i]);
}

__global__ __launch_bounds__(256)
void k_prep(const float* __restrict__ x, unsigned short* __restrict__ xb,
            const float* __restrict__ Wa, unsigned short* __restrict__ WaT,
            const float* __restrict__ Wp, unsigned short* __restrict__ WpT) {
    __shared__ float t[32 * 33];
    const int blk = (int)blockIdx.x;
    const int tid = threadIdx.x;
    if (blk < 4096) {
        const int i = blk * 256 + tid;              // i < 1,048,576 = M*NE/8
        const float4* p = (const float4*)x + (size_t)i * 2;
        float4 a = p[0], b = p[1];
        short8 r;
        r[0] = f2bf(a.x); r[1] = f2bf(a.y); r[2] = f2bf(a.z); r[3] = f2bf(a.w);
        r[4] = f2bf(b.x); r[5] = f2bf(b.y); r[6] = f2bf(b.z); r[7] = f2bf(b.w);
        ((short8*)xb)[i] = r;
    } else if (blk < 4096 + 3072) {
        const int id = blk - 4096;                  // Wa: [NE][3NE] -> [3NE][NE]
        transpose_tile(Wa, WaT, NE, 3 * NE, id % 96, id / 96, tid, t);
    } else {
        const int id = blk - 7168;                  // Wp: [NE][NE] -> [NE][NE]
        transpose_tile(Wp, WpT, NE, NE, id % 32, id / 32, tid, t);
    }
}

// ---------- 128x128 bf16 GEMM, BK=64, swizzled LDS (R5 structure) ----------
// LDS slot s of row r holds global k-seg s^(r&7)  (seg = 16B = 8 bf16).
// Persistent: MODE0 grid 768 x 2 tiles (pair shares n-column); MODE1 grid 512 x 1.
template <int MODE>
__global__ __launch_bounds__(256, 4)
void k_gemm(const unsigned short* __restrict__ A,
            const unsigned short* __restrict__ Bt,
            const float* __restrict__ bias,
            unsigned short* __restrict__ Qb,
            unsigned short* __restrict__ Kb,
            unsigned short* __restrict__ Vt,
            float* __restrict__ out) {
    constexpr int NBN  = (MODE == 0) ? 24 : 8;     // n-blocks
    constexpr int GRID = (MODE == 0) ? 768 : 512;
    constexpr int REPS = (MODE == 0) ? 2 : 1;

    __shared__ alignas(16) short As[128 * 64];
    __shared__ alignas(16) short Bs[128 * 64];
    const int tid = threadIdx.x;
    const int lane = tid & 63, wid = tid >> 6;
    const int quad = lane >> 4, l16 = lane & 15;
    const int wm = (wid >> 1) * 64, wn = (wid & 1) * 64;

    const int srow = lane >> 3;              // 8 rows per wave-call
    const int gseg = (lane & 7) ^ srow;      // swizzled global seg

    // XCD-bijective swizzle (GRID % 8 == 0)
    const int p = (int)blockIdx.x;
    const int ps = (p & 7) * (GRID / 8) + (p >> 3);

    for (int rep = 0; rep < REPS; rep++) {
        const int t = ps + rep * GRID;
        const int n0 = (t % NBN) * 128;
        const int m0 = (t / NBN) * 128;

        f32x4 acc[4][4] = {};

        for (int kk = 0; kk < KD; kk += 64) {
            __syncthreads();
#pragma unroll
            for (int c = 0; c < 4; c++) {
                const int rbase = c * 32 + wid * 8;
                gl_lds16(&A[(size_t)(m0 + rbase + srow) * KD + kk + gseg * 8], &As[rbase * 64]);
                gl_lds16(&Bt[(size_t)(n0 + rbase + srow) * KD + kk + gseg * 8], &Bs[rbase * 64]);
            }
            __syncthreads();
#pragma unroll
            for (int kc = 0; kc < 2; kc++) {
                short8 af[4], bf[4];
#pragma unroll
                for (int tt = 0; tt < 4; tt++) {
                    const int Ra = wm + tt * 16 + l16;
                    af[tt] = *(const short8*)&As[Ra * 64 + (((kc * 4 + quad) ^ (Ra & 7)) * 8)];
                    const int Rb = wn + tt * 16 + l16;
                    bf[tt] = *(const short8*)&Bs[Rb * 64 + (((kc * 4 + quad) ^ (Rb & 7)) * 8)];
                }
#pragma unroll
                for (int mt = 0; mt < 4; mt++)
#pragma unroll
                    for (int nt = 0; nt < 4; nt++)
                        acc[mt][nt] = __builtin_amdgcn_mfma_f32_16x16x32_bf16(
                            af[mt], bf[nt], acc[mt][nt], 0, 0, 0);
            }
        }

#pragma unroll
        for (int nt = 0; nt < 4; nt++) {
            const int n = n0 + wn + nt * 16 + l16;
            const float bv = bias[n];
            if (MODE == 0) {
                const int sel = n >> 10;                  // 0=Q 1=K 2=V (block-uniform)
                const int h = (n & 1023) >> 6;
                const int d = n & 63;
                if (sel == 2) {
                    // V^T: each thread's 4 r-values are contiguous in Vt -> one uint2
#pragma unroll
                    for (int mt = 0; mt < 4; mt++) {
                        const int m = m0 + wm + mt * 16 + quad * 4;   // r base
                        const int b = m >> 11, l = m & 2047;
                        const int bh = b * NH + h;
                        const float v0 = acc[mt][nt][0] + bv;
                        const float v1 = acc[mt][nt][1] + bv;
                        const float v2 = acc[mt][nt][2] + bv;
                        const float v3 = acc[mt][nt][3] + bv;
                        const unsigned w0 = f2bf(v0) | (f2bf(v1) << 16);
                        const unsigned w1 = f2bf(v2) | (f2bf(v3) << 16);
                        *(uint2*)&Vt[(size_t)(bh * 64 + d) * L + l] = make_uint2(w0, w1);
                    }
                } else {
                    // Q pre-scale folds log2(e): attn uses raw v_exp_f32 (2^x)
                    const float qs = 0.125f * 1.44269504f;
#pragma unroll
                    for (int mt = 0; mt < 4; mt++)
#pragma unroll
                        for (int r = 0; r < 4; r++) {
                            const int m = m0 + wm + mt * 16 + quad * 4 + r;
                            const int b = m >> 11, l = m & 2047;
                            const int bh = b * NH + h;
                            const float v = acc[mt][nt][r] + bv;
                            if (sel == 0) Qb[(size_t)(bh * L + l) * 64 + d] = f2bf(v * qs);
                            else          Kb[(size_t)(bh * L + l) * 64 + d] = f2bf(v);
                        }
                }
            } else {
#pragma unroll
                for (int mt = 0; mt < 4; mt++)
#pragma unroll
                    for (int r = 0; r < 4; r++) {
                        const int m = m0 + wm + mt * 16 + quad * 4 + r;
                        out[(size_t)m * NE + n] = acc[mt][nt][r] + bv;
                    }
            }
        }
    }
}

// ---------- causal attention, static softmax, S^T formulation ----------
// R10 structure (verified best): persistent-paired blocks. Grid 256 (1/CU),
// block p=(bh,i): q-tile qb=7-i then qb=i (9 work-units each). Per tile:
// 256 q rows, 8 waves, wave = 32 q rows, K/V tiles of 128, double-buffered
// (64 KB LDS). Tile j+1 staged at top of iter j after raw s_barrier; waited
// vmcnt(0)+s_barrier a full iteration later. S^T = K Q^T: P in C-layout with
// lane = q-col == B-operand shape (k-permutation matched by V's A-operand).
// O^T in regs; LDS transpose restores coalesced stores.
// K LDS: seg^(row&7); V LDS: seg^(row&15). Bank-clean.
// exp: __builtin_amdgcn_exp2f (v_exp_f32; log2e pre-folded in Q).
// P->bf16: v_cvt_pk_bf16_f32 (R16). Denominator: ones-row MFMA (R17).
__global__ __launch_bounds__(512, 2)
void k_attn(const unsigned short* __restrict__ Q,   // [BH][L][64], pre-scaled log2e/8
            const unsigned short* __restrict__ Kb,  // [BH][L][64]
            const unsigned short* __restrict__ Vt,  // [BH][64][L]
            unsigned short* __restrict__ O) {       // [B][L][NE] bf16
    __shared__ alignas(16) short smem[32768];       // K[2][8192] | V[2][8192]; Os[256*72] overlays
    short* Os = smem;

    const int tid = threadIdx.x;
    const int lane = tid & 63, wid = tid >> 6;       // wid 0..7
    const int quad = lane >> 4, l16 = lane & 15;
    const int p = (int)blockIdx.x;
    const int bh = p >> 2, pi = p & 3;
    const size_t base = (size_t)bh * L * 64;
    const int b = bh >> 4, h = bh & 15;

    const int srowK = lane >> 3;
    const int gsegK = (lane & 7) ^ srowK;            // K staging swizzle (row&7)
    const int vrow_off = (lane >> 4);                // V staging: 4 rows/instr
    const int vseg = lane & 15;

    // bf16 1.0 x8 for the denominator MFMA (A = ones -> D[*][q] = sum_k B[k][q])
    const short one_bf = (short)0x3F80;
    const short8 ones = {one_bf, one_bf, one_bf, one_bf, one_bf, one_bf, one_bf, one_bf};

    auto stK = [&](int j, int buf) {
#pragma unroll
        for (int c = 0; c < 2; c++) {
            const int rbase = c * 64 + wid * 8;
            gl_lds16(&Kb[base + (size_t)(j * 128 + rbase + srowK) * 64 + gsegK * 8],
                     &smem[buf * 8192 + rbase * 64]);
        }
    };
    auto stV = [&](int j, int buf) {
#pragma unroll
        for (int c = 0; c < 2; c++) {
            const int rbase = c * 32 + wid * 4;
            const int row = rbase + vrow_off;
            const int gs = vseg ^ (row & 15);
            gl_lds16(&Vt[base + (size_t)row * L + j * 128 + gs * 8],
                     &smem[16384 + buf * 8192 + rbase * 128]);
        }
    };

    for (int half = 0; half < 2; half++) {
        const int qb = half ? pi : 7 - pi;           // heavy tile first
        const int q0 = qb * 256 + wid * 32;
        const int nkv = 2 * qb + 2;                  // k/v tiles of 128

        // previous half's O-store LDS reads are retired before restaging
        __syncthreads();
        stK(0, 0); stV(0, 0);

        short8 qf[2][2];
#pragma unroll
        for (int mt = 0; mt < 2; mt++)
#pragma unroll
            for (int dc = 0; dc < 2; dc++)
                qf[mt][dc] = *(const short8*)&Q[base + (size_t)(q0 + mt * 16 + l16) * 64 + dc * 32 + quad * 8];

        f32x4 o[2][4] = {};
        f32x4 ls[2] = {};                            // denominator accumulators

        for (int j = 0; j < nkv; j++) {
            // K(j),V(j) were issued a full iteration ago (or just above).
            asm volatile("s_waitcnt vmcnt(0)" ::: "memory");
            __builtin_amdgcn_s_barrier();
            // Buffers (j+1)&1 are dead (their readers finished before this barrier).
            if (j < nkv - 1) { stK(j + 1, (j + 1) & 1); stV(j + 1, (j + 1) & 1); }

            const short* Ks = &smem[(j & 1) * 8192];
            const short* Vs = &smem[16384 + (j & 1) * 8192];

            const int dmc = 8 * qb + wid - 4 * j;    // diag chunk (k_start == q_start)
            int chunks = dmc + 1;
            chunks = chunks < 0 ? 0 : (chunks > 4 ? 4 : chunks);

            for (int kc = 0; kc < chunks; kc++) {
                // K fragments (A-operand rows = k)
                short8 kf[2][2];
#pragma unroll
                for (int j0 = 0; j0 < 2; j0++)
#pragma unroll
                    for (int dc = 0; dc < 2; dc++) {
                        const int R = kc * 32 + j0 * 16 + l16;
                        kf[j0][dc] = *(const short8*)&Ks[R * 64 + (((dc * 4 + quad) ^ (R & 7)) * 8)];
                    }
                // S^T[k][q]
                f32x4 st[2][2];
                __builtin_amdgcn_s_setprio(1);
#pragma unroll
                for (int mt = 0; mt < 2; mt++)
#pragma unroll
                    for (int j0 = 0; j0 < 2; j0++) {
                        f32x4 z = {};
                        z = __builtin_amdgcn_mfma_f32_16x16x32_bf16(kf[j0][0], qf[mt][0], z, 0, 0, 0);
                        z = __builtin_amdgcn_mfma_f32_16x16x32_bf16(kf[j0][1], qf[mt][1], z, 0, 0, 0);
                        st[mt][j0] = z;
                    }
                __builtin_amdgcn_s_setprio(0);
                const bool dm = (kc == dmc);
                // p = 2^s (log2e folded into Q); pb via v_cvt_pk_bf16_f32 (RNE)
                short8 pb[2];
#pragma unroll
                for (int mt = 0; mt < 2; mt++) {
                    float pe[8];
#pragma unroll
                    for (int j0 = 0; j0 < 2; j0++)
#pragma unroll
                        for (int r = 0; r < 4; r++) {
                            float pv = __builtin_amdgcn_exp2f(st[mt][j0][r]);
                            if (dm) {
                                const int krel = j0 * 16 + quad * 4 + r;
                                const int qrel = mt * 16 + l16;
                                if (krel > qrel) pv = 0.f;
                            }
                            pe[j0 * 4 + r] = pv;
                        }
                    union { short8 s; unsigned u[4]; } pbu;
#pragma unroll
                    for (int w = 0; w < 4; w++) {
                        unsigned pk;
                        asm("v_cvt_pk_bf16_f32 %0, %1, %2"
                            : "=v"(pk) : "v"(pe[2 * w]), "v"(pe[2 * w + 1]));
                        pbu.u[w] = pk;
                    }
                    pb[mt] = pbu.s;
                    // denominator on the MFMA pipe: ls[mt][*] += sum_k pb[k][q=l16]
                    ls[mt] = __builtin_amdgcn_mfma_f32_16x16x32_bf16(
                        ones, pb[mt], ls[mt], 0, 0, 0);
                }
                // O^T += V^T P^T : A = V-frag (k-permuted to match pb)
#pragma unroll
                for (int dt = 0; dt < 4; dt++) {
                    const int R2 = dt * 16 + l16;
                    const int s16a = kc * 4 + (quad >> 1);
                    const int off = (quad & 1) * 4;
                    s16x4 lo = *(const s16x4*)&Vs[R2 * 128 + ((s16a ^ l16) * 8) + off];
                    s16x4 hi = *(const s16x4*)&Vs[R2 * 128 + (((s16a + 2) ^ l16) * 8) + off];
                    short8 vf = __builtin_shufflevector(lo, hi, 0, 1, 2, 3, 4, 5, 6, 7);
                    __builtin_amdgcn_s_setprio(1);
#pragma unroll
                    for (int mt = 0; mt < 2; mt++)
                        o[mt][dt] = __builtin_amdgcn_mfma_f32_16x16x32_bf16(
                            vf, pb[mt], o[mt][dt], 0, 0, 0);
                    __builtin_amdgcn_s_setprio(0);
                }
            }
        }

        // denominators: ls[mt] rows are identical (A=ones) and quad-uniform
        float inv[2];
#pragma unroll
        for (int mt = 0; mt < 2; mt++)
            inv[mt] = 1.0f / ls[mt][0];

        // O^T -> LDS transpose -> coalesced global store
        __syncthreads();
#pragma unroll
        for (int mt = 0; mt < 2; mt++) {
            const int ql = wid * 32 + mt * 16 + l16;
#pragma unroll
            for (int dt = 0; dt < 4; dt++) {
                unsigned w0 = f2bf(o[mt][dt][0] * inv[mt]) | (f2bf(o[mt][dt][1] * inv[mt]) << 16);
                unsigned w1 = f2bf(o[mt][dt][2] * inv[mt]) | (f2bf(o[mt][dt][3] * inv[mt]) << 16);
                *(uint2*)&Os[ql * 72 + dt * 16 + quad * 4] = make_uint2(w0, w1);
            }
        }
        __syncthreads();
#pragma unroll
        for (int i2 = 0; i2 < 4; i2++) {
            const int id = i2 * 512 + tid;
            const int row = id >> 3, seg = id & 7;
            short8 v = *(const short8*)&Os[row * 72 + seg * 8];
            const int q = qb * 256 + row;
            *(short8*)&O[(size_t)(b * L + q) * NE + h * 64 + seg * 8] = v;
        }
    }
}

extern "C" void kernel_launch(void* const* d_in, const int* in_sizes, int n_in,
                              void* d_out, int out_size, void* d_ws, size_t ws_size,
                              hipStream_t stream) {
    const float* x  = (const float*)d_in[0];
    const float* Wa = (const float*)d_in[1];
    const float* ba = (const float*)d_in[2];
    const float* Wp = (const float*)d_in[3];
    const float* bp = (const float*)d_in[4];
    float* out = (float*)d_out;

    char* ws = (char*)d_ws;
    unsigned short* xb  = (unsigned short*)(ws);                     // 16 MB; reused as O
    unsigned short* WaT = (unsigned short*)(ws + (16u << 20));       //  6 MB
    unsigned short* WpT = (unsigned short*)(ws + (22u << 20));       //  2 MB
    unsigned short* Qb  = (unsigned short*)(ws + (24u << 20));       // 16 MB [BH][L][64]
    unsigned short* Kb  = (unsigned short*)(ws + (40u << 20));       // 16 MB [BH][L][64]
    unsigned short* Vt  = (unsigned short*)(ws + (56u << 20));       // 16 MB [BH][64][L]

    k_prep<<<dim3(8192), 256, 0, stream>>>(x, xb, Wa, WaT, Wp, WpT);

    k_gemm<0><<<dim3(768), 256, 0, stream>>>(xb, WaT, ba, Qb, Kb, Vt, nullptr);

    unsigned short* Ob = xb;
    k_attn<<<dim3(256), 512, 0, stream>>>(Qb, Kb, Vt, Ob);

    k_gemm<1><<<dim3(512), 256, 0, stream>>>(Ob, WpT, bp, nullptr, nullptr, nullptr, out);
}